// Round 1
// baseline (1063.713 us; speedup 1.0000x reference)
//
#include <hip/hip_runtime.h>
#include <math.h>

// ---------------------------------------------------------------------------
// HelmholtzGCN forward: two Helmholtz GCN convs + BN + tanh + log_softmax
// N=100000 nodes, E=1.6M edges, F_IN=128, HID=64, OUT=40, NB=10000
// Outputs: logp [NB,40] then helm_loss1 scalar (concatenated flat, fp32).
// ---------------------------------------------------------------------------

#define BN_EPS 1e-5f

// deg[i] = 1 (self loop); also zero the loss accumulator.
__global__ __launch_bounds__(256) void init_deg(float* __restrict__ deg,
                                                float* __restrict__ loss, int n) {
    int i = blockIdx.x * 256 + threadIdx.x;
    if (i < n) deg[i] = 1.0f;
    if (blockIdx.x == 0 && threadIdx.x == 0) loss[0] = 0.0f;
}

__global__ __launch_bounds__(256) void count_deg(const int* __restrict__ dst,
                                                 float* __restrict__ deg, int e) {
    int i = blockIdx.x * 256 + threadIdx.x;
    if (i < e) atomicAdd(&deg[dst[i]], 1.0f);
}

__global__ __launch_bounds__(256) void make_dinv(float* __restrict__ deg, int n) {
    int i = blockIdx.x * 256 + threadIdx.x;
    if (i < n) deg[i] = rsqrtf(deg[i]);
}

// H[n,64] = X[n,128] @ W[128,64].  One wave per row; lane = out channel.
__global__ __launch_bounds__(256) void gemm_x_w1(const float* __restrict__ X,
                                                 const float* __restrict__ W,
                                                 float* __restrict__ H, int n) {
    __shared__ float w[128 * 64];
    for (int i = threadIdx.x; i < 128 * 64; i += 256) w[i] = W[i];
    __syncthreads();
    int lane = threadIdx.x & 63;
    int row = blockIdx.x * 4 + (threadIdx.x >> 6);
    if (row >= n) return;
    const float4* xr = (const float4*)(X + (size_t)row * 128);
    float acc = 0.0f;
#pragma unroll
    for (int k4 = 0; k4 < 32; ++k4) {
        float4 xv = xr[k4];
        acc += xv.x * w[(k4 * 4 + 0) * 64 + lane];
        acc += xv.y * w[(k4 * 4 + 1) * 64 + lane];
        acc += xv.z * w[(k4 * 4 + 2) * 64 + lane];
        acc += xv.w * w[(k4 * 4 + 3) * 64 + lane];
    }
    H[(size_t)row * 64 + lane] = acc;
}

// H[n,40] = X[n,64] @ W[64,40].  One wave per row; lanes 0..39 active.
__global__ __launch_bounds__(256) void gemm_x_w2(const float* __restrict__ X,
                                                 const float* __restrict__ W,
                                                 float* __restrict__ H, int n) {
    __shared__ float w[64 * 40];
    for (int i = threadIdx.x; i < 64 * 40; i += 256) w[i] = W[i];
    __syncthreads();
    int lane = threadIdx.x & 63;
    int row = blockIdx.x * 4 + (threadIdx.x >> 6);
    if (row >= n) return;
    if (lane < 40) {
        const float4* xr = (const float4*)(X + (size_t)row * 64);
        float acc = 0.0f;
#pragma unroll
        for (int k4 = 0; k4 < 16; ++k4) {
            float4 xv = xr[k4];
            acc += xv.x * w[(k4 * 4 + 0) * 40 + lane];
            acc += xv.y * w[(k4 * 4 + 1) * 40 + lane];
            acc += xv.z * w[(k4 * 4 + 2) * 40 + lane];
            acc += xv.w * w[(k4 * 4 + 3) * 40 + lane];
        }
        H[(size_t)row * 40 + lane] = acc;
    }
}

// AGG[i,:] = dinv[i]^2 * H[i,:]  (self-loop term; initializes every element,
// so no memset of AGG is needed).
template <int C>
__global__ __launch_bounds__(256) void self_loop(const float* __restrict__ dinv,
                                                 const float* __restrict__ H,
                                                 float* __restrict__ AGG, int n) {
    int idx = blockIdx.x * 256 + threadIdx.x;
    if (idx >= n * C) return;
    int row = idx / C;
    float di = dinv[row];
    AGG[idx] = di * di * H[idx];
}

// For each edge e: AGG[dst,:] += dinv[src]*dinv[dst] * H[src,:]
// One wave per edge; lane = channel.
template <int C>
__global__ __launch_bounds__(256) void edge_scatter(const int* __restrict__ src,
                                                    const int* __restrict__ dst,
                                                    const float* __restrict__ dinv,
                                                    const float* __restrict__ H,
                                                    float* __restrict__ AGG, int e) {
    int wid = (blockIdx.x * 256 + threadIdx.x) >> 6;
    int lane = threadIdx.x & 63;
    if (wid >= e) return;
    int s = src[wid];
    int d = dst[wid];
    float c = dinv[s] * dinv[d];
    if (lane < C) {
        atomicAdd(&AGG[(size_t)d * C + lane], c * H[(size_t)s * C + lane]);
    }
}

// out1 = agg + k2*h + b; resid = agg + (k2-1)*h; x = tanh(BN(out1)) in-place
// into h; accumulate sum(resid^2) into loss (1 atomic per block).
__global__ __launch_bounds__(256) void node1(const float* __restrict__ agg,
                                             float* __restrict__ h,
                                             const float* __restrict__ b,
                                             const float* __restrict__ k2p,
                                             const float* __restrict__ g,
                                             const float* __restrict__ be,
                                             const float* __restrict__ m,
                                             const float* __restrict__ v,
                                             float* __restrict__ loss, int n) {
    const float k2 = k2p[0];
    const int total = n * 64;
    float r2sum = 0.0f;
    for (int idx = blockIdx.x * 256 + threadIdx.x; idx < total;
         idx += gridDim.x * 256) {
        int ch = idx & 63;
        float a = agg[idx];
        float hv = h[idx];
        float o = a + k2 * hv + b[ch];
        float resid = a + (k2 - 1.0f) * hv;
        r2sum += resid * resid;
        float xn = (o - m[ch]) * rsqrtf(v[ch] + BN_EPS) * g[ch] + be[ch];
        h[idx] = tanhf(xn);
    }
    // wave reduce
    for (int off = 32; off; off >>= 1) r2sum += __shfl_xor(r2sum, off, 64);
    __shared__ float red[4];
    int wave = threadIdx.x >> 6;
    int lane = threadIdx.x & 63;
    if (lane == 0) red[wave] = r2sum;
    __syncthreads();
    if (threadIdx.x == 0)
        atomicAdd(loss, red[0] + red[1] + red[2] + red[3]);
}

// Per batch node: out2 = agg2 + k2*h2 + b2; y = tanh(BN2(out2));
// logp = y - max - log(sum exp(y - max)).  One wave per batch row.
__global__ __launch_bounds__(256) void finalize(const int* __restrict__ bn,
                                                const float* __restrict__ agg2,
                                                const float* __restrict__ h2,
                                                const float* __restrict__ b2,
                                                const float* __restrict__ k2p,
                                                const float* __restrict__ g,
                                                const float* __restrict__ be,
                                                const float* __restrict__ m,
                                                const float* __restrict__ v,
                                                const float* __restrict__ loss,
                                                float* __restrict__ out, int nb,
                                                float inv_cnt) {
    if (blockIdx.x == 0 && threadIdx.x == 0) out[(size_t)nb * 40] = loss[0] * inv_cnt;
    int wid = (blockIdx.x * 256 + threadIdx.x) >> 6;
    int lane = threadIdx.x & 63;
    if (wid >= nb) return;
    int node = bn[wid];
    float val = 0.0f;
    float t = -INFINITY;
    if (lane < 40) {
        float k2 = k2p[0];
        float o = agg2[(size_t)node * 40 + lane] + k2 * h2[(size_t)node * 40 + lane] +
                  b2[lane];
        val = tanhf((o - m[lane]) * rsqrtf(v[lane] + BN_EPS) * g[lane] + be[lane]);
        t = val;
    }
    float mx = t;
    for (int off = 32; off; off >>= 1) mx = fmaxf(mx, __shfl_xor(mx, off, 64));
    float ex = (lane < 40) ? expf(val - mx) : 0.0f;
    float sum = ex;
    for (int off = 32; off; off >>= 1) sum += __shfl_xor(sum, off, 64);
    if (lane < 40) out[(size_t)wid * 40 + lane] = val - mx - logf(sum);
}

extern "C" void kernel_launch(void* const* d_in, const int* in_sizes, int n_in,
                              void* d_out, int out_size, void* d_ws, size_t ws_size,
                              hipStream_t stream) {
    const float* features = (const float*)d_in[0];
    const int* edge_index = (const int*)d_in[1];
    const int* batch_nodes = (const int*)d_in[2];
    const float* W1 = (const float*)d_in[3];
    const float* b1 = (const float*)d_in[4];
    const float* k2_1 = (const float*)d_in[5];
    const float* W2 = (const float*)d_in[6];
    const float* b2 = (const float*)d_in[7];
    const float* k2_2 = (const float*)d_in[8];
    const float* g1 = (const float*)d_in[9];
    const float* be1 = (const float*)d_in[10];
    const float* m1 = (const float*)d_in[11];
    const float* v1 = (const float*)d_in[12];
    const float* g2 = (const float*)d_in[13];
    const float* be2 = (const float*)d_in[14];
    const float* m2 = (const float*)d_in[15];
    const float* v2 = (const float*)d_in[16];

    const int N = in_sizes[0] / 128;
    const int E = in_sizes[1] / 2;
    const int NB = in_sizes[2];
    const int* src = edge_index;
    const int* dst = edge_index + E;

    // Workspace layout (floats):
    //   deg/dinv [N] | loss [1] (pad to 64) | h1/x [N*64] | agg1/h2 [N*64] | agg2 [N*40]
    float* ws = (float*)d_ws;
    float* deg = ws;                              // becomes dinv in place
    float* loss = ws + N;                         // 1 float
    float* h1 = ws + N + 64;                      // also x (in-place)
    float* agg1 = h1 + (size_t)N * 64;            // also h2 (reused)
    float* agg2 = agg1 + (size_t)N * 64;
    float* x = h1;
    float* h2 = agg1;

    init_deg<<<(N + 255) / 256, 256, 0, stream>>>(deg, loss, N);
    count_deg<<<(E + 255) / 256, 256, 0, stream>>>(dst, deg, E);
    make_dinv<<<(N + 255) / 256, 256, 0, stream>>>(deg, N);

    // conv1
    gemm_x_w1<<<(N + 3) / 4, 256, 0, stream>>>(features, W1, h1, N);
    self_loop<64><<<(N * 64 + 255) / 256, 256, 0, stream>>>(deg, h1, agg1, N);
    edge_scatter<64><<<(E + 3) / 4, 256, 0, stream>>>(src, dst, deg, h1, agg1, E);
    node1<<<2048, 256, 0, stream>>>(agg1, h1, b1, k2_1, g1, be1, m1, v1, loss, N);

    // conv2
    gemm_x_w2<<<(N + 3) / 4, 256, 0, stream>>>(x, W2, h2, N);
    self_loop<40><<<(N * 40 + 255) / 256, 256, 0, stream>>>(deg, h2, agg2, N);
    edge_scatter<40><<<(E + 3) / 4, 256, 0, stream>>>(src, dst, deg, h2, agg2, E);

    finalize<<<(NB + 3) / 4, 256, 0, stream>>>(batch_nodes, agg2, h2, b2, k2_2, g2,
                                               be2, m2, v2, loss, (float*)d_out, NB,
                                               1.0f / ((float)N * 64.0f));
}

// Round 2
// 760.610 us; speedup vs baseline: 1.3985x; 1.3985x over previous
//
#include <hip/hip_runtime.h>
#include <math.h>

// ---------------------------------------------------------------------------
// HelmholtzGCN forward, CSR-gather formulation.
// N=100000 nodes, E=1.6M edges, F_IN=128, HID=64, OUT=40, NB=10000.
// Per call: count deg -> scan -> bucket edges by dst (counting sort) ->
// gemm1 -> fused gather+epilogue (layer1, writes bf16 x + helm loss) ->
// gemm2 -> fused gather+BN+tanh+log_softmax at batch nodes only.
// No fp atomics anywhere (only int atomics for the counting sort).
// ---------------------------------------------------------------------------

#define BN_EPS 1e-5f

// bf16 helpers (bit-level; bf16->f32 exact, f32->bf16 RNE)
__device__ inline unsigned short f2b(float f) {
    unsigned u = __float_as_uint(f);
    unsigned r = (u + 0x7fffu + ((u >> 16) & 1u)) >> 16;
    return (unsigned short)r;
}
__device__ inline float b2f(unsigned short u) {
    return __uint_as_float(((unsigned)u) << 16);
}

__global__ __launch_bounds__(256) void k_zero(int* __restrict__ deg,
                                              float* __restrict__ loss, int n) {
    int i = blockIdx.x * 256 + threadIdx.x;
    if (i < n) deg[i] = 0;
    if (i == 0) loss[0] = 0.0f;
}

__global__ __launch_bounds__(256) void k_count(const int* __restrict__ dst,
                                               int* __restrict__ deg, int e) {
    int i = blockIdx.x * 256 + threadIdx.x;
    if (i < e) atomicAdd(&deg[dst[i]], 1);
}

// block partial sums of deg
__global__ __launch_bounds__(256) void k_scan1(const int* __restrict__ deg,
                                               int* __restrict__ part, int n) {
    __shared__ int s[256];
    int i = blockIdx.x * 256 + threadIdx.x;
    s[threadIdx.x] = (i < n) ? deg[i] : 0;
    __syncthreads();
    for (int off = 128; off; off >>= 1) {
        if (threadIdx.x < off) s[threadIdx.x] += s[threadIdx.x + off];
        __syncthreads();
    }
    if (threadIdx.x == 0) part[blockIdx.x] = s[0];
}

// exclusive scan of block partials (nblk <= 512), in place
__global__ __launch_bounds__(512) void k_scan2(int* __restrict__ part, int nblk) {
    __shared__ int s[512];
    int t = threadIdx.x;
    int v = (t < nblk) ? part[t] : 0;
    s[t] = v;
    __syncthreads();
    for (int off = 1; off < 512; off <<= 1) {
        int a = (t >= off) ? s[t - off] : 0;
        __syncthreads();
        s[t] += a;
        __syncthreads();
    }
    if (t < nblk) part[t] = s[t] - v;  // exclusive
}

// row_ptr / cursor / dinv from deg + scanned partials
__global__ __launch_bounds__(256) void k_scan3(const int* __restrict__ deg,
                                               const int* __restrict__ part,
                                               int* __restrict__ row_ptr,
                                               int* __restrict__ cursor,
                                               float* __restrict__ dinv, int n) {
    __shared__ int s[256];
    int t = threadIdx.x;
    int i = blockIdx.x * 256 + t;
    int v = (i < n) ? deg[i] : 0;
    s[t] = v;
    __syncthreads();
    for (int off = 1; off < 256; off <<= 1) {
        int a = (t >= off) ? s[t - off] : 0;
        __syncthreads();
        s[t] += a;
        __syncthreads();
    }
    if (i < n) {
        int excl = part[blockIdx.x] + s[t] - v;
        row_ptr[i] = excl;
        cursor[i] = excl;
        dinv[i] = rsqrtf((float)(v + 1));  // +1: self loop
        if (i == n - 1) row_ptr[n] = excl + v;
    }
}

// counting-sort edges by dst: sorted_src[row_ptr[d]..] = src of in-edges of d
__global__ __launch_bounds__(256) void k_fill(const int* __restrict__ src,
                                              const int* __restrict__ dst,
                                              int* __restrict__ cursor,
                                              int* __restrict__ sorted, int e) {
    int i = blockIdx.x * 256 + threadIdx.x;
    if (i < e) {
        int p = atomicAdd(&cursor[dst[i]], 1);
        sorted[p] = src[i];
    }
}

// H1[n,64](bf16) = X[n,128](f32) @ W[128,64](f32)
// 4 waves/block, 4 rows/wave. lane -> (kq = lane>>4, cg = (lane&15)*4).
// Each lane accumulates channels [cg,cg+4) over k ≡ kq (mod 4); cross-lane
// reduce over kq groups via shfl_xor(16,32); lanes kq==0 write ushort4.
__global__ __launch_bounds__(256) void k_gemm1(const float* __restrict__ X,
                                               const float* __restrict__ W,
                                               unsigned short* __restrict__ H, int n) {
    __shared__ float w[128 * 64];
    const float4* W4 = (const float4*)W;
    for (int i = threadIdx.x; i < 128 * 16; i += 256) ((float4*)w)[i] = W4[i];
    __syncthreads();
    int lane = threadIdx.x & 63, wave = threadIdx.x >> 6;
    int kq = lane >> 4, cg = (lane & 15) * 4;
    int r0 = (blockIdx.x * 4 + wave) * 4;
    if (r0 >= n) return;
    float4 acc[4];
#pragma unroll
    for (int r = 0; r < 4; ++r) acc[r] = make_float4(0.f, 0.f, 0.f, 0.f);
#pragma unroll 8
    for (int k0 = 0; k0 < 128; k0 += 4) {
        int k = k0 + kq;
        float4 wv = *(const float4*)&w[k * 64 + cg];
#pragma unroll
        for (int r = 0; r < 4; ++r) {
            int rr = min(r0 + r, n - 1);
            float xv = X[(size_t)rr * 128 + k];
            acc[r].x += xv * wv.x;
            acc[r].y += xv * wv.y;
            acc[r].z += xv * wv.z;
            acc[r].w += xv * wv.w;
        }
    }
#pragma unroll
    for (int r = 0; r < 4; ++r) {
        float4 a = acc[r];
        a.x += __shfl_xor(a.x, 16, 64); a.y += __shfl_xor(a.y, 16, 64);
        a.z += __shfl_xor(a.z, 16, 64); a.w += __shfl_xor(a.w, 16, 64);
        a.x += __shfl_xor(a.x, 32, 64); a.y += __shfl_xor(a.y, 32, 64);
        a.z += __shfl_xor(a.z, 32, 64); a.w += __shfl_xor(a.w, 32, 64);
        if (kq == 0 && r0 + r < n) {
            ushort4 p;
            p.x = f2b(a.x); p.y = f2b(a.y); p.z = f2b(a.z); p.w = f2b(a.w);
            *(ushort4*)&H[(size_t)(r0 + r) * 64 + cg] = p;
        }
    }
}

// H2[n,40](f32) = Xb[n,64](bf16) @ W2[64,40](f32); W2 zero-padded to 64 cols in LDS
__global__ __launch_bounds__(256) void k_gemm2(const unsigned short* __restrict__ X,
                                               const float* __restrict__ W,
                                               float* __restrict__ H, int n) {
    __shared__ float w[64 * 64];
    for (int i = threadIdx.x; i < 64 * 64; i += 256) {
        int k = i >> 6, c = i & 63;
        w[i] = (c < 40) ? W[k * 40 + c] : 0.f;
    }
    __syncthreads();
    int lane = threadIdx.x & 63, wave = threadIdx.x >> 6;
    int kq = lane >> 4, cg = (lane & 15) * 4;
    int r0 = (blockIdx.x * 4 + wave) * 4;
    if (r0 >= n) return;
    float4 acc[4];
#pragma unroll
    for (int r = 0; r < 4; ++r) acc[r] = make_float4(0.f, 0.f, 0.f, 0.f);
#pragma unroll 8
    for (int k0 = 0; k0 < 64; k0 += 4) {
        int k = k0 + kq;
        float4 wv = *(const float4*)&w[k * 64 + cg];
#pragma unroll
        for (int r = 0; r < 4; ++r) {
            int rr = min(r0 + r, n - 1);
            float xv = b2f(X[(size_t)rr * 64 + k]);
            acc[r].x += xv * wv.x;
            acc[r].y += xv * wv.y;
            acc[r].z += xv * wv.z;
            acc[r].w += xv * wv.w;
        }
    }
#pragma unroll
    for (int r = 0; r < 4; ++r) {
        float4 a = acc[r];
        a.x += __shfl_xor(a.x, 16, 64); a.y += __shfl_xor(a.y, 16, 64);
        a.z += __shfl_xor(a.z, 16, 64); a.w += __shfl_xor(a.w, 16, 64);
        a.x += __shfl_xor(a.x, 32, 64); a.y += __shfl_xor(a.y, 32, 64);
        a.z += __shfl_xor(a.z, 32, 64); a.w += __shfl_xor(a.w, 32, 64);
        if (kq == 0 && cg < 40 && r0 + r < n) {
            *(float4*)&H[(size_t)(r0 + r) * 40 + cg] = a;
        }
    }
}

// Layer-1 fused: per node (one wave), gather in-edges via CSR, add self loop,
// epilogue (bias/BN/tanh) -> bf16 x, plus helm-loss block reduction.
// agg = dd*(sum_s dinv[s]*h[s] + dd*h[d])  (dd factored out)
__global__ __launch_bounds__(256) void k_conv1(const int* __restrict__ row_ptr,
                                               const int* __restrict__ sorted,
                                               const float* __restrict__ dinv,
                                               const unsigned short* __restrict__ h1,
                                               unsigned short* __restrict__ x,
                                               const float* __restrict__ b1,
                                               const float* __restrict__ k2p,
                                               const float* __restrict__ g,
                                               const float* __restrict__ be,
                                               const float* __restrict__ m,
                                               const float* __restrict__ v,
                                               float* __restrict__ loss, int n) {
    int lane = threadIdx.x & 63, wave = threadIdx.x >> 6;
    int node = blockIdx.x * 4 + wave;
    float r2 = 0.0f;
    if (node < n) {
        int beg = row_ptr[node], end = row_ptr[node + 1];
        float dd = dinv[node];
        float hs = b2f(h1[(size_t)node * 64 + lane]);
        float acc = dd * hs;
        for (int e = beg; e < end; ++e) {
            int s = __builtin_amdgcn_readfirstlane(sorted[e]);
            acc += dinv[s] * b2f(h1[(size_t)s * 64 + lane]);
        }
        float a = dd * acc;
        float k2 = k2p[0];
        float o = a + k2 * hs + b1[lane];
        float resid = a + (k2 - 1.0f) * hs;
        r2 = resid * resid;
        float xn = (o - m[lane]) * rsqrtf(v[lane] + BN_EPS) * g[lane] + be[lane];
        x[(size_t)node * 64 + lane] = f2b(tanhf(xn));
    }
    for (int off = 32; off; off >>= 1) r2 += __shfl_xor(r2, off, 64);
    __shared__ float red[4];
    if (lane == 0) red[wave] = r2;
    __syncthreads();
    if (threadIdx.x == 0) atomicAdd(loss, red[0] + red[1] + red[2] + red[3]);
}

// Layer-2 fused, BATCH NODES ONLY: gather + self loop + BN + tanh + log_softmax.
__global__ __launch_bounds__(256) void k_conv2(const int* __restrict__ bn,
                                               const int* __restrict__ row_ptr,
                                               const int* __restrict__ sorted,
                                               const float* __restrict__ dinv,
                                               const float* __restrict__ h2,
                                               const float* __restrict__ b2,
                                               const float* __restrict__ k2p,
                                               const float* __restrict__ g,
                                               const float* __restrict__ be,
                                               const float* __restrict__ m,
                                               const float* __restrict__ v,
                                               const float* __restrict__ loss,
                                               float* __restrict__ out, int nb,
                                               float inv_cnt) {
    if (blockIdx.x == 0 && threadIdx.x == 0) out[(size_t)nb * 40] = loss[0] * inv_cnt;
    int lane = threadIdx.x & 63, wave = threadIdx.x >> 6;
    int wid = blockIdx.x * 4 + wave;
    if (wid >= nb) return;
    int node = bn[wid];
    int beg = row_ptr[node], end = row_ptr[node + 1];
    float dd = dinv[node];
    int ch = (lane < 40) ? lane : 39;  // clamp: lanes >=40 compute garbage, discarded
    float hs = h2[(size_t)node * 40 + ch];
    float acc = dd * hs;
    for (int e = beg; e < end; ++e) {
        int s = __builtin_amdgcn_readfirstlane(sorted[e]);
        acc += dinv[s] * h2[(size_t)s * 40 + ch];
    }
    float val = 0.0f, t = -INFINITY;
    if (lane < 40) {
        float k2 = k2p[0];
        float o = dd * acc + k2 * hs + b2[lane];
        val = tanhf((o - m[lane]) * rsqrtf(v[lane] + BN_EPS) * g[lane] + be[lane]);
        t = val;
    }
    float mx = t;
    for (int off = 32; off; off >>= 1) mx = fmaxf(mx, __shfl_xor(mx, off, 64));
    float ex = (lane < 40) ? expf(val - mx) : 0.0f;
    float sum = ex;
    for (int off = 32; off; off >>= 1) sum += __shfl_xor(sum, off, 64);
    if (lane < 40) out[(size_t)wid * 40 + lane] = val - mx - logf(sum);
}

extern "C" void kernel_launch(void* const* d_in, const int* in_sizes, int n_in,
                              void* d_out, int out_size, void* d_ws, size_t ws_size,
                              hipStream_t stream) {
    const float* features = (const float*)d_in[0];
    const int* edge_index = (const int*)d_in[1];
    const int* batch_nodes = (const int*)d_in[2];
    const float* W1 = (const float*)d_in[3];
    const float* b1 = (const float*)d_in[4];
    const float* k2_1 = (const float*)d_in[5];
    const float* W2 = (const float*)d_in[6];
    const float* b2 = (const float*)d_in[7];
    const float* k2_2 = (const float*)d_in[8];
    const float* g1 = (const float*)d_in[9];
    const float* be1 = (const float*)d_in[10];
    const float* m1 = (const float*)d_in[11];
    const float* v1 = (const float*)d_in[12];
    const float* g2 = (const float*)d_in[13];
    const float* be2 = (const float*)d_in[14];
    const float* m2 = (const float*)d_in[15];
    const float* v2 = (const float*)d_in[16];

    const int N = in_sizes[0] / 128;
    const int E = in_sizes[1] / 2;
    const int NB = in_sizes[2];
    const int* src = edge_index;
    const int* dst = edge_index + E;
    const int NBLK = (N + 255) / 256;  // must be <= 512 (N <= 131072)

    // Workspace layout (u32 units, 64-aligned blocks): ~49.6 MB total
    unsigned* ws = (unsigned*)d_ws;
    auto align64 = [](size_t o) { return (o + 63) & ~(size_t)63; };
    size_t o = 0;
    int* deg = (int*)(ws + o);            o = align64(o + N);
    int* row_ptr = (int*)(ws + o);        o = align64(o + N + 1);
    int* cursor = (int*)(ws + o);         o = align64(o + N);
    int* part = (int*)(ws + o);           o = align64(o + 512);
    float* dinv = (float*)(ws + o);       o = align64(o + N);
    float* loss = (float*)(ws + o);       o = align64(o + 64);
    int* sorted = (int*)(ws + o);         o = align64(o + E);
    unsigned short* h1 = (unsigned short*)(ws + o); o = align64(o + (size_t)N * 32);
    unsigned short* x  = (unsigned short*)(ws + o); o = align64(o + (size_t)N * 32);
    float* h2 = (float*)(ws + o);         o = align64(o + (size_t)N * 40);

    // CSR build
    k_zero<<<NBLK, 256, 0, stream>>>(deg, loss, N);
    k_count<<<(E + 255) / 256, 256, 0, stream>>>(dst, deg, E);
    k_scan1<<<NBLK, 256, 0, stream>>>(deg, part, N);
    k_scan2<<<1, 512, 0, stream>>>(part, NBLK);
    k_scan3<<<NBLK, 256, 0, stream>>>(deg, part, row_ptr, cursor, dinv, N);
    k_fill<<<(E + 255) / 256, 256, 0, stream>>>(src, dst, cursor, sorted, E);

    // layer 1
    k_gemm1<<<(N + 15) / 16, 256, 0, stream>>>(features, W1, h1, N);
    k_conv1<<<(N + 3) / 4, 256, 0, stream>>>(row_ptr, sorted, dinv, h1, x, b1, k2_1,
                                             g1, be1, m1, v1, loss, N);
    // layer 2 (outputs needed only at batch nodes)
    k_gemm2<<<(N + 15) / 16, 256, 0, stream>>>(x, W2, h2, N);
    k_conv2<<<(NB + 3) / 4, 256, 0, stream>>>(batch_nodes, row_ptr, sorted, dinv, h2,
                                              b2, k2_2, g2, be2, m2, v2, loss,
                                              (float*)d_out, NB,
                                              1.0f / ((float)N * 64.0f));
}

// Round 3
// 491.359 us; speedup vs baseline: 2.1648x; 1.5480x over previous
//
#include <hip/hip_runtime.h>
#include <math.h>

// ---------------------------------------------------------------------------
// HelmholtzGCN forward, CSR-gather formulation, latency-optimized gathers.
// N=100000 nodes, E=1.6M edges, F_IN=128, HID=64, OUT=40, NB=10000.
// conv gathers: wave = 1 node; two 32-lane halves each cover all channels as
// pairs; halves take alternate edges; 4-deep unroll with clamped indices ->
// 8 gathers in flight per wave (latency-bound fix for R2's serial edge loop).
// Loss: per-block partials + separate reduce (no same-address fp atomics).
// ---------------------------------------------------------------------------

#define BN_EPS 1e-5f

__device__ inline unsigned short f2b(float f) {
    unsigned u = __float_as_uint(f);
    unsigned r = (u + 0x7fffu + ((u >> 16) & 1u)) >> 16;
    return (unsigned short)r;
}
__device__ inline float b2f_lo(unsigned u) { return __uint_as_float(u << 16); }
__device__ inline float b2f_hi(unsigned u) { return __uint_as_float(u & 0xffff0000u); }

// deg=0; block 0 also precomputes per-channel BN scale/shift tables:
//   A[c] = g*rsqrt(v+eps),  S[c] = (b - m)*A + be    (xn = (a + k2*h)*A + S)
__global__ __launch_bounds__(256) void k_zero(int* __restrict__ deg, int n,
                                              const float* __restrict__ b1,
                                              const float* __restrict__ g1,
                                              const float* __restrict__ be1,
                                              const float* __restrict__ m1,
                                              const float* __restrict__ v1,
                                              const float* __restrict__ b2,
                                              const float* __restrict__ g2,
                                              const float* __restrict__ be2,
                                              const float* __restrict__ m2,
                                              const float* __restrict__ v2,
                                              float* __restrict__ A1,
                                              float* __restrict__ S1,
                                              float* __restrict__ A2,
                                              float* __restrict__ S2) {
    int i = blockIdx.x * 256 + threadIdx.x;
    if (i < n) deg[i] = 0;
    if (blockIdx.x == 0) {
        int t = threadIdx.x;
        if (t < 64) {
            float a = g1[t] * rsqrtf(v1[t] + BN_EPS);
            A1[t] = a;
            S1[t] = (b1[t] - m1[t]) * a + be1[t];
        } else if (t < 104) {
            int c = t - 64;
            float a = g2[c] * rsqrtf(v2[c] + BN_EPS);
            A2[c] = a;
            S2[c] = (b2[c] - m2[c]) * a + be2[c];
        }
    }
}

__global__ __launch_bounds__(256) void k_count(const int* __restrict__ dst,
                                               int* __restrict__ deg, int e) {
    int i = blockIdx.x * 256 + threadIdx.x;
    int base = i * 4;
    if (base + 3 < e) {
        int4 d = *(const int4*)&dst[base];
        atomicAdd(&deg[d.x], 1);
        atomicAdd(&deg[d.y], 1);
        atomicAdd(&deg[d.z], 1);
        atomicAdd(&deg[d.w], 1);
    } else {
        for (int j = base; j < e; ++j) atomicAdd(&deg[dst[j]], 1);
    }
}

__global__ __launch_bounds__(256) void k_scan1(const int* __restrict__ deg,
                                               int* __restrict__ part, int n) {
    __shared__ int s[256];
    int i = blockIdx.x * 256 + threadIdx.x;
    s[threadIdx.x] = (i < n) ? deg[i] : 0;
    __syncthreads();
    for (int off = 128; off; off >>= 1) {
        if (threadIdx.x < off) s[threadIdx.x] += s[threadIdx.x + off];
        __syncthreads();
    }
    if (threadIdx.x == 0) part[blockIdx.x] = s[0];
}

__global__ __launch_bounds__(512) void k_scan2(int* __restrict__ part, int nblk) {
    __shared__ int s[512];
    int t = threadIdx.x;
    int v = (t < nblk) ? part[t] : 0;
    s[t] = v;
    __syncthreads();
    for (int off = 1; off < 512; off <<= 1) {
        int a = (t >= off) ? s[t - off] : 0;
        __syncthreads();
        s[t] += a;
        __syncthreads();
    }
    if (t < nblk) part[t] = s[t] - v;
}

__global__ __launch_bounds__(256) void k_scan3(const int* __restrict__ deg,
                                               const int* __restrict__ part,
                                               int* __restrict__ row_ptr,
                                               int* __restrict__ cursor,
                                               float* __restrict__ dinv, int n) {
    __shared__ int s[256];
    int t = threadIdx.x;
    int i = blockIdx.x * 256 + t;
    int v = (i < n) ? deg[i] : 0;
    s[t] = v;
    __syncthreads();
    for (int off = 1; off < 256; off <<= 1) {
        int a = (t >= off) ? s[t - off] : 0;
        __syncthreads();
        s[t] += a;
        __syncthreads();
    }
    if (i < n) {
        int excl = part[blockIdx.x] + s[t] - v;
        row_ptr[i] = excl;
        cursor[i] = excl;
        dinv[i] = rsqrtf((float)(v + 1));
        if (i == n - 1) row_ptr[n] = excl + v;
    }
}

__global__ __launch_bounds__(256) void k_fill(const int* __restrict__ src,
                                              const int* __restrict__ dst,
                                              int* __restrict__ cursor,
                                              int* __restrict__ sorted, int e) {
    int i = blockIdx.x * 256 + threadIdx.x;
    int base = i * 4;
    if (base + 3 < e) {
        int4 s = *(const int4*)&src[base];
        int4 d = *(const int4*)&dst[base];
        sorted[atomicAdd(&cursor[d.x], 1)] = s.x;
        sorted[atomicAdd(&cursor[d.y], 1)] = s.y;
        sorted[atomicAdd(&cursor[d.z], 1)] = s.z;
        sorted[atomicAdd(&cursor[d.w], 1)] = s.w;
    } else {
        for (int j = base; j < e; ++j) sorted[atomicAdd(&cursor[dst[j]], 1)] = src[j];
    }
}

// H1[n,64](bf16) = X[n,128](f32) @ W[128,64](f32)
__global__ __launch_bounds__(256) void k_gemm1(const float* __restrict__ X,
                                               const float* __restrict__ W,
                                               unsigned short* __restrict__ H, int n) {
    __shared__ float w[128 * 64];
    const float4* W4 = (const float4*)W;
    for (int i = threadIdx.x; i < 128 * 16; i += 256) ((float4*)w)[i] = W4[i];
    __syncthreads();
    int lane = threadIdx.x & 63, wave = threadIdx.x >> 6;
    int kq = lane >> 4, cg = (lane & 15) * 4;
    int r0 = (blockIdx.x * 4 + wave) * 4;
    if (r0 >= n) return;
    float4 acc[4];
#pragma unroll
    for (int r = 0; r < 4; ++r) acc[r] = make_float4(0.f, 0.f, 0.f, 0.f);
#pragma unroll 8
    for (int k0 = 0; k0 < 128; k0 += 4) {
        int k = k0 + kq;
        float4 wv = *(const float4*)&w[k * 64 + cg];
#pragma unroll
        for (int r = 0; r < 4; ++r) {
            int rr = min(r0 + r, n - 1);
            float xv = X[(size_t)rr * 128 + k];
            acc[r].x += xv * wv.x;
            acc[r].y += xv * wv.y;
            acc[r].z += xv * wv.z;
            acc[r].w += xv * wv.w;
        }
    }
#pragma unroll
    for (int r = 0; r < 4; ++r) {
        float4 a = acc[r];
        a.x += __shfl_xor(a.x, 16, 64); a.y += __shfl_xor(a.y, 16, 64);
        a.z += __shfl_xor(a.z, 16, 64); a.w += __shfl_xor(a.w, 16, 64);
        a.x += __shfl_xor(a.x, 32, 64); a.y += __shfl_xor(a.y, 32, 64);
        a.z += __shfl_xor(a.z, 32, 64); a.w += __shfl_xor(a.w, 32, 64);
        if (kq == 0 && r0 + r < n) {
            ushort4 p;
            p.x = f2b(a.x); p.y = f2b(a.y); p.z = f2b(a.z); p.w = f2b(a.w);
            *(ushort4*)&H[(size_t)(r0 + r) * 64 + cg] = p;
        }
    }
}

// H2[n,40](f32) = Xb[n,64](bf16) @ W2[64,40](f32)
__global__ __launch_bounds__(256) void k_gemm2(const unsigned short* __restrict__ X,
                                               const float* __restrict__ W,
                                               float* __restrict__ H, int n) {
    __shared__ float w[64 * 64];
    for (int i = threadIdx.x; i < 64 * 64; i += 256) {
        int k = i >> 6, c = i & 63;
        w[i] = (c < 40) ? W[k * 40 + c] : 0.f;
    }
    __syncthreads();
    int lane = threadIdx.x & 63, wave = threadIdx.x >> 6;
    int kq = lane >> 4, cg = (lane & 15) * 4;
    int r0 = (blockIdx.x * 4 + wave) * 4;
    if (r0 >= n) return;
    float4 acc[4];
#pragma unroll
    for (int r = 0; r < 4; ++r) acc[r] = make_float4(0.f, 0.f, 0.f, 0.f);
#pragma unroll 8
    for (int k0 = 0; k0 < 64; k0 += 4) {
        int k = k0 + kq;
        float4 wv = *(const float4*)&w[k * 64 + cg];
#pragma unroll
        for (int r = 0; r < 4; ++r) {
            int rr = min(r0 + r, n - 1);
            float xv = b2f_lo((unsigned)X[(size_t)rr * 64 + k]);
            acc[r].x += xv * wv.x;
            acc[r].y += xv * wv.y;
            acc[r].z += xv * wv.z;
            acc[r].w += xv * wv.w;
        }
    }
#pragma unroll
    for (int r = 0; r < 4; ++r) {
        float4 a = acc[r];
        a.x += __shfl_xor(a.x, 16, 64); a.y += __shfl_xor(a.y, 16, 64);
        a.z += __shfl_xor(a.z, 16, 64); a.w += __shfl_xor(a.w, 16, 64);
        a.x += __shfl_xor(a.x, 32, 64); a.y += __shfl_xor(a.y, 32, 64);
        a.z += __shfl_xor(a.z, 32, 64); a.w += __shfl_xor(a.w, 32, 64);
        if (kq == 0 && cg < 40 && r0 + r < n) {
            *(float4*)&H[(size_t)(r0 + r) * 40 + cg] = a;
        }
    }
}

// Layer-1 fused gather+epilogue. Wave = node. half = lane>>5 takes alternate
// edges; c2 = lane&31 covers channel pair (2c2, 2c2+1) as packed bf16.
// 4-deep unroll: 8 edges in flight per wave. Partials (no atomic) for loss.
__global__ __launch_bounds__(256) void k_conv1(const int* __restrict__ row_ptr,
                                               const int* __restrict__ sorted,
                                               const float* __restrict__ dinv,
                                               const unsigned* __restrict__ h1,  // [n,32] packed pairs
                                               unsigned* __restrict__ x,         // [n,32] packed pairs
                                               const float* __restrict__ A1,
                                               const float* __restrict__ S1,
                                               const float* __restrict__ k2p,
                                               float* __restrict__ partial, int n) {
    int lane = threadIdx.x & 63, wave = threadIdx.x >> 6;
    int half = lane >> 5, c2 = lane & 31;
    int node = blockIdx.x * 4 + wave;
    float r2 = 0.0f;
    if (node < n) {
        int beg = row_ptr[node], end = row_ptr[node + 1];
        float dd = dinv[node];
        unsigned hp = h1[(size_t)node * 32 + c2];
        float hx = b2f_lo(hp), hy = b2f_hi(hp);
        float ax = half ? 0.f : dd * hx;
        float ay = half ? 0.f : dd * hy;
        for (int eb = beg; eb < end; eb += 8) {
            int i0 = eb + half, i1 = i0 + 2, i2 = i0 + 4, i3 = i0 + 6;
            int s0 = sorted[min(i0, end - 1)];
            int s1 = sorted[min(i1, end - 1)];
            int s2 = sorted[min(i2, end - 1)];
            int s3 = sorted[min(i3, end - 1)];
            float d0 = (i0 < end) ? dinv[s0] : 0.f;
            float d1 = (i1 < end) ? dinv[s1] : 0.f;
            float d2 = (i2 < end) ? dinv[s2] : 0.f;
            float d3 = (i3 < end) ? dinv[s3] : 0.f;
            unsigned p0 = h1[(size_t)s0 * 32 + c2];
            unsigned p1 = h1[(size_t)s1 * 32 + c2];
            unsigned p2 = h1[(size_t)s2 * 32 + c2];
            unsigned p3 = h1[(size_t)s3 * 32 + c2];
            ax += d0 * b2f_lo(p0); ay += d0 * b2f_hi(p0);
            ax += d1 * b2f_lo(p1); ay += d1 * b2f_hi(p1);
            ax += d2 * b2f_lo(p2); ay += d2 * b2f_hi(p2);
            ax += d3 * b2f_lo(p3); ay += d3 * b2f_hi(p3);
        }
        ax += __shfl_xor(ax, 32, 64);
        ay += __shfl_xor(ay, 32, 64);
        if (half == 0) {
            float a_x = dd * ax, a_y = dd * ay;
            float k2 = k2p[0];
            float rx = a_x + (k2 - 1.0f) * hx;
            float ry = a_y + (k2 - 1.0f) * hy;
            r2 = rx * rx + ry * ry;
            float2 Ap = *(const float2*)&A1[2 * c2];
            float2 Sp = *(const float2*)&S1[2 * c2];
            float xnx = tanhf((a_x + k2 * hx) * Ap.x + Sp.x);
            float xny = tanhf((a_y + k2 * hy) * Ap.y + Sp.y);
            x[(size_t)node * 32 + c2] = (unsigned)f2b(xnx) | ((unsigned)f2b(xny) << 16);
        }
    }
    for (int off = 32; off; off >>= 1) r2 += __shfl_xor(r2, off, 64);
    __shared__ float red[4];
    if (lane == 0) red[wave] = r2;
    __syncthreads();
    if (threadIdx.x == 0) partial[blockIdx.x] = red[0] + red[1] + red[2] + red[3];
}

// reduce partials -> out[nb*40] = loss/ (n*64)
__global__ __launch_bounds__(1024) void k_loss(const float* __restrict__ partial,
                                               int nparts, float* __restrict__ out,
                                               size_t idx, float inv_cnt) {
    float s = 0.f;
    for (int i = threadIdx.x; i < nparts; i += 1024) s += partial[i];
    for (int off = 32; off; off >>= 1) s += __shfl_xor(s, off, 64);
    __shared__ float red[16];
    int wv = threadIdx.x >> 6, ln = threadIdx.x & 63;
    if (ln == 0) red[wv] = s;
    __syncthreads();
    if (threadIdx.x == 0) {
        float t = 0.f;
        for (int i = 0; i < 16; ++i) t += red[i];
        out[idx] = t * inv_cnt;
    }
}

// Layer-2 fused gather + BN + tanh + log_softmax at batch nodes only.
// Same half/pair structure; pairs p=0..19 cover 40 f32 channels.
__global__ __launch_bounds__(256) void k_conv2(const int* __restrict__ bn,
                                               const int* __restrict__ row_ptr,
                                               const int* __restrict__ sorted,
                                               const float* __restrict__ dinv,
                                               const float* __restrict__ h2,
                                               const float* __restrict__ A2,
                                               const float* __restrict__ S2,
                                               const float* __restrict__ k2p,
                                               float* __restrict__ out, int nb) {
    int lane = threadIdx.x & 63, wave = threadIdx.x >> 6;
    int wid = blockIdx.x * 4 + wave;
    if (wid >= nb) return;
    int half = lane >> 5, c2 = lane & 31;
    int p = min(c2, 19);
    int node = bn[wid];
    int beg = row_ptr[node], end = row_ptr[node + 1];
    float dd = dinv[node];
    float2 hs = *(const float2*)&h2[(size_t)node * 40 + 2 * p];
    float ax = half ? 0.f : dd * hs.x;
    float ay = half ? 0.f : dd * hs.y;
    for (int eb = beg; eb < end; eb += 8) {
        int i0 = eb + half, i1 = i0 + 2, i2 = i0 + 4, i3 = i0 + 6;
        int s0 = sorted[min(i0, end - 1)];
        int s1 = sorted[min(i1, end - 1)];
        int s2 = sorted[min(i2, end - 1)];
        int s3 = sorted[min(i3, end - 1)];
        float d0 = (i0 < end) ? dinv[s0] : 0.f;
        float d1 = (i1 < end) ? dinv[s1] : 0.f;
        float d2 = (i2 < end) ? dinv[s2] : 0.f;
        float d3 = (i3 < end) ? dinv[s3] : 0.f;
        float2 p0 = *(const float2*)&h2[(size_t)s0 * 40 + 2 * p];
        float2 p1 = *(const float2*)&h2[(size_t)s1 * 40 + 2 * p];
        float2 p2 = *(const float2*)&h2[(size_t)s2 * 40 + 2 * p];
        float2 p3 = *(const float2*)&h2[(size_t)s3 * 40 + 2 * p];
        ax += d0 * p0.x; ay += d0 * p0.y;
        ax += d1 * p1.x; ay += d1 * p1.y;
        ax += d2 * p2.x; ay += d2 * p2.y;
        ax += d3 * p3.x; ay += d3 * p3.y;
    }
    ax += __shfl_xor(ax, 32, 64);
    ay += __shfl_xor(ay, 32, 64);
    float k2 = k2p[0];
    float2 Ap = *(const float2*)&A2[2 * p];
    float2 Sp = *(const float2*)&S2[2 * p];
    float tx = tanhf((dd * ax + k2 * hs.x) * Ap.x + Sp.x);
    float ty = tanhf((dd * ay + k2 * hs.y) * Ap.y + Sp.y);
    bool act = (half == 0) && (c2 < 20);
    float mx = act ? fmaxf(tx, ty) : -INFINITY;
    for (int off = 32; off; off >>= 1) mx = fmaxf(mx, __shfl_xor(mx, off, 64));
    float es = act ? (expf(tx - mx) + expf(ty - mx)) : 0.f;
    for (int off = 32; off; off >>= 1) es += __shfl_xor(es, off, 64);
    if (act) {
        float ls = mx + logf(es);
        float2 o = make_float2(tx - ls, ty - ls);
        *(float2*)&out[(size_t)wid * 40 + 2 * p] = o;
    }
}

extern "C" void kernel_launch(void* const* d_in, const int* in_sizes, int n_in,
                              void* d_out, int out_size, void* d_ws, size_t ws_size,
                              hipStream_t stream) {
    const float* features = (const float*)d_in[0];
    const int* edge_index = (const int*)d_in[1];
    const int* batch_nodes = (const int*)d_in[2];
    const float* W1 = (const float*)d_in[3];
    const float* b1 = (const float*)d_in[4];
    const float* k2_1 = (const float*)d_in[5];
    const float* W2 = (const float*)d_in[6];
    const float* b2 = (const float*)d_in[7];
    const float* k2_2 = (const float*)d_in[8];
    const float* g1 = (const float*)d_in[9];
    const float* be1 = (const float*)d_in[10];
    const float* m1 = (const float*)d_in[11];
    const float* v1 = (const float*)d_in[12];
    const float* g2 = (const float*)d_in[13];
    const float* be2 = (const float*)d_in[14];
    const float* m2 = (const float*)d_in[15];
    const float* v2 = (const float*)d_in[16];

    const int N = in_sizes[0] / 128;
    const int E = in_sizes[1] / 2;
    const int NB = in_sizes[2];
    const int* src = edge_index;
    const int* dst = edge_index + E;
    const int NBLK = (N + 255) / 256;        // <= 512
    const int NPART = (N + 3) / 4;           // k_conv1 grid

    unsigned* ws = (unsigned*)d_ws;
    auto align64 = [](size_t o) { return (o + 63) & ~(size_t)63; };
    size_t o = 0;
    int* deg = (int*)(ws + o);            o = align64(o + N);
    int* row_ptr = (int*)(ws + o);        o = align64(o + N + 1);
    int* cursor = (int*)(ws + o);         o = align64(o + N);
    int* part = (int*)(ws + o);           o = align64(o + 512);
    float* dinv = (float*)(ws + o);       o = align64(o + N);
    float* A1 = (float*)(ws + o);         o = align64(o + 64);
    float* S1 = (float*)(ws + o);         o = align64(o + 64);
    float* A2 = (float*)(ws + o);         o = align64(o + 40);
    float* S2 = (float*)(ws + o);         o = align64(o + 40);
    float* partial = (float*)(ws + o);    o = align64(o + NPART);
    int* sorted = (int*)(ws + o);         o = align64(o + E);
    unsigned* h1 = (unsigned*)(ws + o);   o = align64(o + (size_t)N * 32);  // bf16 pairs
    unsigned* x  = (unsigned*)(ws + o);   o = align64(o + (size_t)N * 32);
    float* h2 = (float*)(ws + o);         o = align64(o + (size_t)N * 40);

    k_zero<<<NBLK, 256, 0, stream>>>(deg, N, b1, g1, be1, m1, v1, b2, g2, be2, m2,
                                     v2, A1, S1, A2, S2);
    k_count<<<(E / 4 + 255) / 256 + 1, 256, 0, stream>>>(dst, deg, E);
    k_scan1<<<NBLK, 256, 0, stream>>>(deg, part, N);
    k_scan2<<<1, 512, 0, stream>>>(part, NBLK);
    k_scan3<<<NBLK, 256, 0, stream>>>(deg, part, row_ptr, cursor, dinv, N);
    k_fill<<<(E / 4 + 255) / 256 + 1, 256, 0, stream>>>(src, dst, cursor, sorted, E);

    k_gemm1<<<(N + 15) / 16, 256, 0, stream>>>(features, W1, (unsigned short*)h1, N);
    k_conv1<<<NPART, 256, 0, stream>>>(row_ptr, sorted, dinv, h1, x, A1, S1, k2_1,
                                       partial, N);
    k_loss<<<1, 1024, 0, stream>>>(partial, NPART, (float*)d_out, (size_t)NB * 40,
                                   1.0f / ((float)N * 64.0f));
    k_gemm2<<<(N + 15) / 16, 256, 0, stream>>>((const unsigned short*)x, W2, h2, N);
    k_conv2<<<(NB + 3) / 4, 256, 0, stream>>>(batch_nodes, row_ptr, sorted, dinv, h2,
                                              A2, S2, k2_2, (float*)d_out, NB);
}

// Round 4
// 349.468 us; speedup vs baseline: 3.0438x; 1.4060x over previous
//
#include <hip/hip_runtime.h>
#include <math.h>

// ---------------------------------------------------------------------------
// HelmholtzGCN forward, CSR-gather formulation.
// R4: CSR build via hierarchical bucket partition (no random 4B scatters):
//   k_hist  : LDS histogram of 512 coarse buckets (dst>>8)
//   k_bscan : scan bucket counts -> bucket_base / bucket_cursor
//   k_part  : partition packed edges into bucket runs (localized writes)
//   k_bucket: per-bucket LDS fine sort -> sorted[], row_ptr[], dinv[]
// Then gemm1 -> fused gather+epilogue -> gemm2 -> fused gather+softmax.
// ---------------------------------------------------------------------------

#define BN_EPS 1e-5f
#define NB_BKT 512    // max coarse buckets (N <= 131072)
#define BKT_CAP 6144  // LDS edge capacity per bucket (avg 4096, ~5 sigma headroom)

__device__ inline unsigned short f2b(float f) {
    unsigned u = __float_as_uint(f);
    unsigned r = (u + 0x7fffu + ((u >> 16) & 1u)) >> 16;
    return (unsigned short)r;
}
__device__ inline float b2f_lo(unsigned u) { return __uint_as_float(u << 16); }
__device__ inline float b2f_hi(unsigned u) { return __uint_as_float(u & 0xffff0000u); }

// zero bucket counts; precompute BN scale/shift tables:
//   A[c] = g*rsqrt(v+eps),  S[c] = (b - m)*A + be
__global__ __launch_bounds__(512) void k_init(unsigned* __restrict__ bucket_count,
                                              const float* __restrict__ b1,
                                              const float* __restrict__ g1,
                                              const float* __restrict__ be1,
                                              const float* __restrict__ m1,
                                              const float* __restrict__ v1,
                                              const float* __restrict__ b2,
                                              const float* __restrict__ g2,
                                              const float* __restrict__ be2,
                                              const float* __restrict__ m2,
                                              const float* __restrict__ v2,
                                              float* __restrict__ A1,
                                              float* __restrict__ S1,
                                              float* __restrict__ A2,
                                              float* __restrict__ S2) {
    int t = threadIdx.x;
    bucket_count[t] = 0;
    if (t < 64) {
        float a = g1[t] * rsqrtf(v1[t] + BN_EPS);
        A1[t] = a;
        S1[t] = (b1[t] - m1[t]) * a + be1[t];
    } else if (t < 104) {
        int c = t - 64;
        float a = g2[c] * rsqrtf(v2[c] + BN_EPS);
        A2[c] = a;
        S2[c] = (b2[c] - m2[c]) * a + be2[c];
    }
}

// coarse bucket histogram via LDS
__global__ __launch_bounds__(256) void k_hist(const int* __restrict__ dst, int e,
                                              unsigned* __restrict__ bucket_count) {
    __shared__ unsigned h[NB_BKT];
    for (int i = threadIdx.x; i < NB_BKT; i += 256) h[i] = 0;
    __syncthreads();
    int t = blockIdx.x * 256 + threadIdx.x;
    for (int base = t * 4; base < e; base += gridDim.x * 1024) {
        if (base + 3 < e) {
            int4 d = *(const int4*)&dst[base];
            atomicAdd(&h[(unsigned)d.x >> 8], 1u);
            atomicAdd(&h[(unsigned)d.y >> 8], 1u);
            atomicAdd(&h[(unsigned)d.z >> 8], 1u);
            atomicAdd(&h[(unsigned)d.w >> 8], 1u);
        } else {
            for (int j = base; j < e; ++j) atomicAdd(&h[(unsigned)dst[j] >> 8], 1u);
        }
    }
    __syncthreads();
    for (int i = threadIdx.x; i < NB_BKT; i += 256)
        if (h[i]) atomicAdd(&bucket_count[i], h[i]);
}

// exclusive scan of bucket counts -> bucket_base[0..512], bucket_cursor
__global__ __launch_bounds__(512) void k_bscan(const unsigned* __restrict__ bucket_count,
                                               unsigned* __restrict__ bucket_base,
                                               unsigned* __restrict__ bucket_cursor) {
    __shared__ unsigned sc[NB_BKT];
    int t = threadIdx.x;
    unsigned v = bucket_count[t];
    sc[t] = v;
    __syncthreads();
    for (int off = 1; off < NB_BKT; off <<= 1) {
        unsigned a = (t >= off) ? sc[t - off] : 0u;
        __syncthreads();
        sc[t] += a;
        __syncthreads();
    }
    bucket_base[t + 1] = sc[t];
    bucket_cursor[t] = sc[t] - v;
    if (t == 0) bucket_base[0] = 0;
}

// partition edges into coarse buckets; packed u32 = (dst&255)<<24 | src
__global__ __launch_bounds__(256) void k_part(const int* __restrict__ src,
                                              const int* __restrict__ dst, int e,
                                              unsigned* __restrict__ bucket_cursor,
                                              unsigned* __restrict__ part, int nblk) {
    __shared__ unsigned h[NB_BKT];
    __shared__ unsigned gbase[NB_BKT];
    __shared__ unsigned cur[NB_BKT];
    int chunk = ((e + nblk - 1) / nblk + 3) & ~3;
    int c0 = blockIdx.x * chunk;
    int c1 = min(c0 + chunk, e);
    if (c0 >= e) return;
    for (int i = threadIdx.x; i < NB_BKT; i += 256) h[i] = 0;
    __syncthreads();
    for (int i = c0 + threadIdx.x * 4; i < c1; i += 1024) {
        if (i + 3 < c1) {
            int4 d = *(const int4*)&dst[i];
            atomicAdd(&h[(unsigned)d.x >> 8], 1u);
            atomicAdd(&h[(unsigned)d.y >> 8], 1u);
            atomicAdd(&h[(unsigned)d.z >> 8], 1u);
            atomicAdd(&h[(unsigned)d.w >> 8], 1u);
        } else {
            for (int j = i; j < c1; ++j) atomicAdd(&h[(unsigned)dst[j] >> 8], 1u);
        }
    }
    __syncthreads();
    for (int i = threadIdx.x; i < NB_BKT; i += 256) {
        unsigned c = h[i];
        gbase[i] = c ? atomicAdd(&bucket_cursor[i], c) : 0u;
        cur[i] = 0;
    }
    __syncthreads();
    for (int i = c0 + threadIdx.x * 4; i < c1; i += 1024) {
        if (i + 3 < c1) {
            int4 s = *(const int4*)&src[i];
            int4 d = *(const int4*)&dst[i];
            unsigned b0 = (unsigned)d.x >> 8, b1 = (unsigned)d.y >> 8;
            unsigned b2 = (unsigned)d.z >> 8, b3 = (unsigned)d.w >> 8;
            unsigned r0 = atomicAdd(&cur[b0], 1u);
            unsigned r1 = atomicAdd(&cur[b1], 1u);
            unsigned r2 = atomicAdd(&cur[b2], 1u);
            unsigned r3 = atomicAdd(&cur[b3], 1u);
            part[gbase[b0] + r0] = (((unsigned)d.x & 255u) << 24) | (unsigned)s.x;
            part[gbase[b1] + r1] = (((unsigned)d.y & 255u) << 24) | (unsigned)s.y;
            part[gbase[b2] + r2] = (((unsigned)d.z & 255u) << 24) | (unsigned)s.z;
            part[gbase[b3] + r3] = (((unsigned)d.w & 255u) << 24) | (unsigned)s.w;
        } else {
            for (int j = i; j < c1; ++j) {
                unsigned b = (unsigned)dst[j] >> 8;
                unsigned r = atomicAdd(&cur[b], 1u);
                part[gbase[b] + r] = (((unsigned)dst[j] & 255u) << 24) | (unsigned)src[j];
            }
        }
    }
}

// per-bucket fine sort: sorted[], row_ptr[], dinv[] for 256 local dst nodes
__global__ __launch_bounds__(256) void k_bucket(const unsigned* __restrict__ part,
                                                const unsigned* __restrict__ bucket_base,
                                                unsigned* __restrict__ sorted,
                                                int* __restrict__ row_ptr,
                                                float* __restrict__ dinv, int n) {
    __shared__ unsigned buf[BKT_CAP];
    __shared__ unsigned hist[256];
    __shared__ unsigned sc[256];
    __shared__ unsigned cur[256];
    int b = blockIdx.x;
    unsigned beg = bucket_base[b], end = bucket_base[b + 1];
    int cnt = (int)(end - beg);
    int dst0 = b << 8;
    int nloc = min(256, n - dst0);
    int t = threadIdx.x;
    hist[t] = 0;
    __syncthreads();
    bool fit = (cnt <= BKT_CAP);
    for (int i = t; i < cnt; i += 256) {
        unsigned p = part[beg + i];
        if (fit) buf[i] = p;
        atomicAdd(&hist[p >> 24], 1u);
    }
    __syncthreads();
    unsigned v = hist[t];
    sc[t] = v;
    __syncthreads();
    for (int off = 1; off < 256; off <<= 1) {
        unsigned a = (t >= off) ? sc[t - off] : 0u;
        __syncthreads();
        sc[t] += a;
        __syncthreads();
    }
    unsigned excl = sc[t] - v;
    if (t < nloc) {
        row_ptr[dst0 + t] = (int)(beg + excl);
        dinv[dst0 + t] = rsqrtf((float)(v + 1u));
    }
    if (t == 0 && dst0 + nloc == n) row_ptr[n] = (int)end;
    cur[t] = excl;
    __syncthreads();
    for (int i = t; i < cnt; i += 256) {
        unsigned p = fit ? buf[i] : part[beg + i];
        unsigned r = atomicAdd(&cur[p >> 24], 1u);
        sorted[beg + r] = p & 0xFFFFFFu;
    }
}

// H1[n,64](bf16) = X[n,128](f32) @ W[128,64](f32)
__global__ __launch_bounds__(256) void k_gemm1(const float* __restrict__ X,
                                               const float* __restrict__ W,
                                               unsigned short* __restrict__ H, int n) {
    __shared__ float w[128 * 64];
    const float4* W4 = (const float4*)W;
    for (int i = threadIdx.x; i < 128 * 16; i += 256) ((float4*)w)[i] = W4[i];
    __syncthreads();
    int lane = threadIdx.x & 63, wave = threadIdx.x >> 6;
    int kq = lane >> 4, cg = (lane & 15) * 4;
    int r0 = (blockIdx.x * 4 + wave) * 4;
    if (r0 >= n) return;
    float4 acc[4];
#pragma unroll
    for (int r = 0; r < 4; ++r) acc[r] = make_float4(0.f, 0.f, 0.f, 0.f);
#pragma unroll 8
    for (int k0 = 0; k0 < 128; k0 += 4) {
        int k = k0 + kq;
        float4 wv = *(const float4*)&w[k * 64 + cg];
#pragma unroll
        for (int r = 0; r < 4; ++r) {
            int rr = min(r0 + r, n - 1);
            float xv = X[(size_t)rr * 128 + k];
            acc[r].x += xv * wv.x;
            acc[r].y += xv * wv.y;
            acc[r].z += xv * wv.z;
            acc[r].w += xv * wv.w;
        }
    }
#pragma unroll
    for (int r = 0; r < 4; ++r) {
        float4 a = acc[r];
        a.x += __shfl_xor(a.x, 16, 64); a.y += __shfl_xor(a.y, 16, 64);
        a.z += __shfl_xor(a.z, 16, 64); a.w += __shfl_xor(a.w, 16, 64);
        a.x += __shfl_xor(a.x, 32, 64); a.y += __shfl_xor(a.y, 32, 64);
        a.z += __shfl_xor(a.z, 32, 64); a.w += __shfl_xor(a.w, 32, 64);
        if (kq == 0 && r0 + r < n) {
            ushort4 p;
            p.x = f2b(a.x); p.y = f2b(a.y); p.z = f2b(a.z); p.w = f2b(a.w);
            *(ushort4*)&H[(size_t)(r0 + r) * 64 + cg] = p;
        }
    }
}

// H2[n,40](f32) = Xb[n,64](bf16) @ W2[64,40](f32)
__global__ __launch_bounds__(256) void k_gemm2(const unsigned short* __restrict__ X,
                                               const float* __restrict__ W,
                                               float* __restrict__ H, int n) {
    __shared__ float w[64 * 64];
    for (int i = threadIdx.x; i < 64 * 64; i += 256) {
        int k = i >> 6, c = i & 63;
        w[i] = (c < 40) ? W[k * 40 + c] : 0.f;
    }
    __syncthreads();
    int lane = threadIdx.x & 63, wave = threadIdx.x >> 6;
    int kq = lane >> 4, cg = (lane & 15) * 4;
    int r0 = (blockIdx.x * 4 + wave) * 4;
    if (r0 >= n) return;
    float4 acc[4];
#pragma unroll
    for (int r = 0; r < 4; ++r) acc[r] = make_float4(0.f, 0.f, 0.f, 0.f);
#pragma unroll 8
    for (int k0 = 0; k0 < 64; k0 += 4) {
        int k = k0 + kq;
        float4 wv = *(const float4*)&w[k * 64 + cg];
#pragma unroll
        for (int r = 0; r < 4; ++r) {
            int rr = min(r0 + r, n - 1);
            float xv = b2f_lo((unsigned)X[(size_t)rr * 64 + k]);
            acc[r].x += xv * wv.x;
            acc[r].y += xv * wv.y;
            acc[r].z += xv * wv.z;
            acc[r].w += xv * wv.w;
        }
    }
#pragma unroll
    for (int r = 0; r < 4; ++r) {
        float4 a = acc[r];
        a.x += __shfl_xor(a.x, 16, 64); a.y += __shfl_xor(a.y, 16, 64);
        a.z += __shfl_xor(a.z, 16, 64); a.w += __shfl_xor(a.w, 16, 64);
        a.x += __shfl_xor(a.x, 32, 64); a.y += __shfl_xor(a.y, 32, 64);
        a.z += __shfl_xor(a.z, 32, 64); a.w += __shfl_xor(a.w, 32, 64);
        if (kq == 0 && cg < 40 && r0 + r < n) {
            *(float4*)&H[(size_t)(r0 + r) * 40 + cg] = a;
        }
    }
}

// Layer-1 fused gather+epilogue. Wave = node; two 32-lane halves take
// alternate edges; c2 = lane&31 covers bf16 channel pair. 8 gathers in flight.
__global__ __launch_bounds__(256) void k_conv1(const int* __restrict__ row_ptr,
                                               const unsigned* __restrict__ sorted,
                                               const float* __restrict__ dinv,
                                               const unsigned* __restrict__ h1,
                                               unsigned* __restrict__ x,
                                               const float* __restrict__ A1,
                                               const float* __restrict__ S1,
                                               const float* __restrict__ k2p,
                                               float* __restrict__ partial, int n) {
    int lane = threadIdx.x & 63, wave = threadIdx.x >> 6;
    int half = lane >> 5, c2 = lane & 31;
    int node = blockIdx.x * 4 + wave;
    float r2 = 0.0f;
    if (node < n) {
        int beg = row_ptr[node], end = row_ptr[node + 1];
        float dd = dinv[node];
        unsigned hp = h1[(size_t)node * 32 + c2];
        float hx = b2f_lo(hp), hy = b2f_hi(hp);
        float ax = half ? 0.f : dd * hx;
        float ay = half ? 0.f : dd * hy;
        for (int eb = beg; eb < end; eb += 8) {
            int i0 = eb + half, i1 = i0 + 2, i2 = i0 + 4, i3 = i0 + 6;
            int s0 = sorted[min(i0, end - 1)];
            int s1 = sorted[min(i1, end - 1)];
            int s2 = sorted[min(i2, end - 1)];
            int s3 = sorted[min(i3, end - 1)];
            float d0 = (i0 < end) ? dinv[s0] : 0.f;
            float d1 = (i1 < end) ? dinv[s1] : 0.f;
            float d2 = (i2 < end) ? dinv[s2] : 0.f;
            float d3 = (i3 < end) ? dinv[s3] : 0.f;
            unsigned p0 = h1[(size_t)s0 * 32 + c2];
            unsigned p1 = h1[(size_t)s1 * 32 + c2];
            unsigned p2 = h1[(size_t)s2 * 32 + c2];
            unsigned p3 = h1[(size_t)s3 * 32 + c2];
            ax += d0 * b2f_lo(p0); ay += d0 * b2f_hi(p0);
            ax += d1 * b2f_lo(p1); ay += d1 * b2f_hi(p1);
            ax += d2 * b2f_lo(p2); ay += d2 * b2f_hi(p2);
            ax += d3 * b2f_lo(p3); ay += d3 * b2f_hi(p3);
        }
        ax += __shfl_xor(ax, 32, 64);
        ay += __shfl_xor(ay, 32, 64);
        if (half == 0) {
            float a_x = dd * ax, a_y = dd * ay;
            float k2 = k2p[0];
            float rx = a_x + (k2 - 1.0f) * hx;
            float ry = a_y + (k2 - 1.0f) * hy;
            r2 = rx * rx + ry * ry;
            float2 Ap = *(const float2*)&A1[2 * c2];
            float2 Sp = *(const float2*)&S1[2 * c2];
            float xnx = tanhf((a_x + k2 * hx) * Ap.x + Sp.x);
            float xny = tanhf((a_y + k2 * hy) * Ap.y + Sp.y);
            x[(size_t)node * 32 + c2] = (unsigned)f2b(xnx) | ((unsigned)f2b(xny) << 16);
        }
    }
    for (int off = 32; off; off >>= 1) r2 += __shfl_xor(r2, off, 64);
    __shared__ float red[4];
    if (lane == 0) red[wave] = r2;
    __syncthreads();
    if (threadIdx.x == 0) partial[blockIdx.x] = red[0] + red[1] + red[2] + red[3];
}

__global__ __launch_bounds__(1024) void k_loss(const float* __restrict__ partial,
                                               int nparts, float* __restrict__ out,
                                               size_t idx, float inv_cnt) {
    float s = 0.f;
    for (int i = threadIdx.x; i < nparts; i += 1024) s += partial[i];
    for (int off = 32; off; off >>= 1) s += __shfl_xor(s, off, 64);
    __shared__ float red[16];
    int wv = threadIdx.x >> 6, ln = threadIdx.x & 63;
    if (ln == 0) red[wv] = s;
    __syncthreads();
    if (threadIdx.x == 0) {
        float t = 0.f;
        for (int i = 0; i < 16; ++i) t += red[i];
        out[idx] = t * inv_cnt;
    }
}

// Layer-2 fused gather + BN + tanh + log_softmax at batch nodes only.
__global__ __launch_bounds__(256) void k_conv2(const int* __restrict__ bn,
                                               const int* __restrict__ row_ptr,
                                               const unsigned* __restrict__ sorted,
                                               const float* __restrict__ dinv,
                                               const float* __restrict__ h2,
                                               const float* __restrict__ A2,
                                               const float* __restrict__ S2,
                                               const float* __restrict__ k2p,
                                               float* __restrict__ out, int nb) {
    int lane = threadIdx.x & 63, wave = threadIdx.x >> 6;
    int wid = blockIdx.x * 4 + wave;
    if (wid >= nb) return;
    int half = lane >> 5, c2 = lane & 31;
    int p = min(c2, 19);
    int node = bn[wid];
    int beg = row_ptr[node], end = row_ptr[node + 1];
    float dd = dinv[node];
    float2 hs = *(const float2*)&h2[(size_t)node * 40 + 2 * p];
    float ax = half ? 0.f : dd * hs.x;
    float ay = half ? 0.f : dd * hs.y;
    for (int eb = beg; eb < end; eb += 8) {
        int i0 = eb + half, i1 = i0 + 2, i2 = i0 + 4, i3 = i0 + 6;
        int s0 = sorted[min(i0, end - 1)];
        int s1 = sorted[min(i1, end - 1)];
        int s2 = sorted[min(i2, end - 1)];
        int s3 = sorted[min(i3, end - 1)];
        float d0 = (i0 < end) ? dinv[s0] : 0.f;
        float d1 = (i1 < end) ? dinv[s1] : 0.f;
        float d2 = (i2 < end) ? dinv[s2] : 0.f;
        float d3 = (i3 < end) ? dinv[s3] : 0.f;
        float2 p0 = *(const float2*)&h2[(size_t)s0 * 40 + 2 * p];
        float2 p1 = *(const float2*)&h2[(size_t)s1 * 40 + 2 * p];
        float2 p2 = *(const float2*)&h2[(size_t)s2 * 40 + 2 * p];
        float2 p3 = *(const float2*)&h2[(size_t)s3 * 40 + 2 * p];
        ax += d0 * p0.x; ay += d0 * p0.y;
        ax += d1 * p1.x; ay += d1 * p1.y;
        ax += d2 * p2.x; ay += d2 * p2.y;
        ax += d3 * p3.x; ay += d3 * p3.y;
    }
    ax += __shfl_xor(ax, 32, 64);
    ay += __shfl_xor(ay, 32, 64);
    float k2 = k2p[0];
    float2 Ap = *(const float2*)&A2[2 * p];
    float2 Sp = *(const float2*)&S2[2 * p];
    float tx = tanhf((dd * ax + k2 * hs.x) * Ap.x + Sp.x);
    float ty = tanhf((dd * ay + k2 * hs.y) * Ap.y + Sp.y);
    bool act = (half == 0) && (c2 < 20);
    float mx = act ? fmaxf(tx, ty) : -INFINITY;
    for (int off = 32; off; off >>= 1) mx = fmaxf(mx, __shfl_xor(mx, off, 64));
    float es = act ? (expf(tx - mx) + expf(ty - mx)) : 0.f;
    for (int off = 32; off; off >>= 1) es += __shfl_xor(es, off, 64);
    if (act) {
        float ls = mx + logf(es);
        float2 o = make_float2(tx - ls, ty - ls);
        *(float2*)&out[(size_t)wid * 40 + 2 * p] = o;
    }
}

extern "C" void kernel_launch(void* const* d_in, const int* in_sizes, int n_in,
                              void* d_out, int out_size, void* d_ws, size_t ws_size,
                              hipStream_t stream) {
    const float* features = (const float*)d_in[0];
    const int* edge_index = (const int*)d_in[1];
    const int* batch_nodes = (const int*)d_in[2];
    const float* W1 = (const float*)d_in[3];
    const float* b1 = (const float*)d_in[4];
    const float* k2_1 = (const float*)d_in[5];
    const float* W2 = (const float*)d_in[6];
    const float* b2 = (const float*)d_in[7];
    const float* k2_2 = (const float*)d_in[8];
    const float* g1 = (const float*)d_in[9];
    const float* be1 = (const float*)d_in[10];
    const float* m1 = (const float*)d_in[11];
    const float* v1 = (const float*)d_in[12];
    const float* g2 = (const float*)d_in[13];
    const float* be2 = (const float*)d_in[14];
    const float* m2 = (const float*)d_in[15];
    const float* v2 = (const float*)d_in[16];

    const int N = in_sizes[0] / 128;
    const int E = in_sizes[1] / 2;
    const int NB = in_sizes[2];
    const int* src = edge_index;
    const int* dst = edge_index + E;
    const int NPART = (N + 3) / 4;      // k_conv1 grid
    const int NBKT = (N + 255) >> 8;    // used coarse buckets (<= 512)
    const int PBLK = 96;                // k_part blocks

    unsigned* ws = (unsigned*)d_ws;
    auto align64 = [](size_t o) { return (o + 63) & ~(size_t)63; };
    size_t o = 0;
    int* row_ptr = (int*)(ws + o);            o = align64(o + N + 1);
    float* dinv = (float*)(ws + o);           o = align64(o + N);
    float* A1 = (float*)(ws + o);             o = align64(o + 64);
    float* S1 = (float*)(ws + o);             o = align64(o + 64);
    float* A2 = (float*)(ws + o);             o = align64(o + 64);
    float* S2 = (float*)(ws + o);             o = align64(o + 64);
    unsigned* bucket_count = ws + o;          o = align64(o + NB_BKT);
    unsigned* bucket_base = ws + o;           o = align64(o + NB_BKT + 1);
    unsigned* bucket_cursor = ws + o;         o = align64(o + NB_BKT);
    float* partial = (float*)(ws + o);        o = align64(o + NPART);
    unsigned* sorted = ws + o;                o = align64(o + E);
    unsigned* h1 = ws + o;                    o = align64(o + (size_t)N * 32);
    unsigned* x = ws + o;                     o = align64(o + (size_t)N * 32);
    float* h2 = (float*)(ws + o);             o = align64(o + (size_t)N * 40);
    unsigned* part = (unsigned*)h2;           // aliases h2 (dead before gemm2)

    // CSR build (hierarchical partition)
    k_init<<<1, 512, 0, stream>>>(bucket_count, b1, g1, be1, m1, v1, b2, g2, be2,
                                  m2, v2, A1, S1, A2, S2);
    k_hist<<<512, 256, 0, stream>>>(dst, E, bucket_count);
    k_bscan<<<1, 512, 0, stream>>>(bucket_count, bucket_base, bucket_cursor);
    k_part<<<PBLK, 256, 0, stream>>>(src, dst, E, bucket_cursor, part, PBLK);
    k_bucket<<<NBKT, 256, 0, stream>>>(part, bucket_base, sorted, row_ptr, dinv, N);

    // layer 1
    k_gemm1<<<(N + 15) / 16, 256, 0, stream>>>(features, W1, (unsigned short*)h1, N);
    k_conv1<<<NPART, 256, 0, stream>>>(row_ptr, sorted, dinv, h1, x, A1, S1, k2_1,
                                       partial, N);
    k_loss<<<1, 1024, 0, stream>>>(partial, NPART, (float*)d_out, (size_t)NB * 40,
                                   1.0f / ((float)N * 64.0f));
    // layer 2
    k_gemm2<<<(N + 15) / 16, 256, 0, stream>>>((const unsigned short*)x, W2, h2, N);
    k_conv2<<<(NB + 3) / 4, 256, 0, stream>>>(batch_nodes, row_ptr, sorted, dinv, h2,
                                              A2, S2, k2_2, (float*)d_out, NB);
}

// Round 5
// 323.340 us; speedup vs baseline: 3.2898x; 1.0808x over previous
//
#include <hip/hip_runtime.h>
#include <math.h>

// ---------------------------------------------------------------------------
// HelmholtzGCN forward. R5: padded (idx,coef) edge-pair stream.
//   k_init    : zero bucket counts + BN scale/shift tables
//   k_part    : partition packed edges into fixed-stride coarse buckets
//   k_deg     : per-bucket degree/dinv/rowinfo (padded-to-8 offsets)
//   k_scatter : scatter (src, dinv[src]) uint2 pairs + zero-coef padding
//   gemm1 -> conv1 (gather, fused BN/tanh/loss) -> gemm2(bf16 out) -> conv2
// Conv inner loop: 2x dwordx4 pair loads + 4 h-row loads per 8 edges,
// no clamps/cndmasks; fast tanh via v_exp+v_rcp.
// ---------------------------------------------------------------------------

#define BN_EPS 1e-5f
#define NB_BKT 512
#define RCAP 4608      // raw per-bucket capacity (mean 3125, ~26 sigma)
#define PSTRIDE 6656   // padded per-bucket stride (RCAP + 256*8 max pad)

__device__ inline unsigned short f2b(float f) {
    unsigned u = __float_as_uint(f);
    unsigned r = (u + 0x7fffu + ((u >> 16) & 1u)) >> 16;
    return (unsigned short)r;
}
__device__ inline float b2f_lo(unsigned u) { return __uint_as_float(u << 16); }
__device__ inline float b2f_hi(unsigned u) { return __uint_as_float(u & 0xffff0000u); }
__device__ inline unsigned pk2(float a, float b) {
    return (unsigned)f2b(a) | ((unsigned)f2b(b) << 16);
}
__device__ inline float tanh_fast(float x) {
    float e = __expf(2.0f * x);
    return 1.0f - 2.0f * __builtin_amdgcn_rcpf(e + 1.0f);
}

__global__ __launch_bounds__(512) void k_init(unsigned* __restrict__ bcnt,
                                              const float* __restrict__ b1,
                                              const float* __restrict__ g1,
                                              const float* __restrict__ be1,
                                              const float* __restrict__ m1,
                                              const float* __restrict__ v1,
                                              const float* __restrict__ b2,
                                              const float* __restrict__ g2,
                                              const float* __restrict__ be2,
                                              const float* __restrict__ m2,
                                              const float* __restrict__ v2,
                                              float* __restrict__ A1,
                                              float* __restrict__ S1,
                                              float* __restrict__ A2,
                                              float* __restrict__ S2) {
    int t = threadIdx.x;
    bcnt[t] = 0;
    if (t < 64) {
        float a = g1[t] * rsqrtf(v1[t] + BN_EPS);
        A1[t] = a;
        S1[t] = (b1[t] - m1[t]) * a + be1[t];
    } else if (t < 104) {
        int c = t - 64;
        float a = g2[c] * rsqrtf(v2[c] + BN_EPS);
        A2[c] = a;
        S2[c] = (b2[c] - m2[c]) * a + be2[c];
    }
}

// partition edges into fixed-stride buckets; packed u32 = (dst&255)<<24 | src
__global__ __launch_bounds__(256) void k_part(const int* __restrict__ src,
                                              const int* __restrict__ dst, int e,
                                              unsigned* __restrict__ bcnt,
                                              unsigned* __restrict__ part, int nblk) {
    __shared__ unsigned h[NB_BKT];
    __shared__ unsigned gbase[NB_BKT];
    __shared__ unsigned cur[NB_BKT];
    int chunk = ((e + nblk - 1) / nblk + 3) & ~3;
    int c0 = blockIdx.x * chunk;
    int c1 = min(c0 + chunk, e);
    if (c0 >= e) return;
    for (int i = threadIdx.x; i < NB_BKT; i += 256) h[i] = 0;
    __syncthreads();
    for (int i = c0 + threadIdx.x * 4; i < c1; i += 1024) {
        if (i + 3 < c1) {
            int4 d = *(const int4*)&dst[i];
            atomicAdd(&h[(unsigned)d.x >> 8], 1u);
            atomicAdd(&h[(unsigned)d.y >> 8], 1u);
            atomicAdd(&h[(unsigned)d.z >> 8], 1u);
            atomicAdd(&h[(unsigned)d.w >> 8], 1u);
        } else {
            for (int j = i; j < c1; ++j) atomicAdd(&h[(unsigned)dst[j] >> 8], 1u);
        }
    }
    __syncthreads();
    for (int i = threadIdx.x; i < NB_BKT; i += 256) {
        unsigned c = h[i];
        gbase[i] = c ? (i * RCAP + atomicAdd(&bcnt[i], c)) : 0u;
        cur[i] = 0;
    }
    __syncthreads();
    for (int i = c0 + threadIdx.x * 4; i < c1; i += 1024) {
        if (i + 3 < c1) {
            int4 s = *(const int4*)&src[i];
            int4 d = *(const int4*)&dst[i];
            unsigned b0 = (unsigned)d.x >> 8, b1 = (unsigned)d.y >> 8;
            unsigned b2 = (unsigned)d.z >> 8, b3 = (unsigned)d.w >> 8;
            unsigned p0 = gbase[b0] + atomicAdd(&cur[b0], 1u);
            unsigned p1 = gbase[b1] + atomicAdd(&cur[b1], 1u);
            unsigned p2 = gbase[b2] + atomicAdd(&cur[b2], 1u);
            unsigned p3 = gbase[b3] + atomicAdd(&cur[b3], 1u);
            if (p0 < (b0 + 1) * RCAP) part[p0] = (((unsigned)d.x & 255u) << 24) | (unsigned)s.x;
            if (p1 < (b1 + 1) * RCAP) part[p1] = (((unsigned)d.y & 255u) << 24) | (unsigned)s.y;
            if (p2 < (b2 + 1) * RCAP) part[p2] = (((unsigned)d.z & 255u) << 24) | (unsigned)s.z;
            if (p3 < (b3 + 1) * RCAP) part[p3] = (((unsigned)d.w & 255u) << 24) | (unsigned)s.w;
        } else {
            for (int j = i; j < c1; ++j) {
                unsigned b = (unsigned)dst[j] >> 8;
                unsigned p = gbase[b] + atomicAdd(&cur[b], 1u);
                if (p < (b + 1) * RCAP)
                    part[p] = (((unsigned)dst[j] & 255u) << 24) | (unsigned)src[j];
            }
        }
    }
}

// per-bucket degree/dinv + padded row offsets (rowinfo = beg | pdeg<<32)
__global__ __launch_bounds__(256) void k_deg(const unsigned* __restrict__ part,
                                             const unsigned* __restrict__ bcnt,
                                             unsigned long long* __restrict__ rowinfo,
                                             float* __restrict__ dinv, int n) {
    __shared__ unsigned hist[256];
    __shared__ unsigned sc[256];
    int b = blockIdx.x;
    int cnt = (int)min(bcnt[b], (unsigned)RCAP);
    unsigned base = b * RCAP;
    int dst0 = b << 8;
    int nloc = min(256, n - dst0);
    int t = threadIdx.x;
    hist[t] = 0;
    __syncthreads();
    for (int i = t; i < cnt; i += 256) atomicAdd(&hist[part[base + i] >> 24], 1u);
    __syncthreads();
    unsigned c = hist[t];
    unsigned pcnt = (t < nloc) ? ((c + 7u) & ~7u) : 0u;
    sc[t] = pcnt;
    __syncthreads();
    for (int off = 1; off < 256; off <<= 1) {
        unsigned a = (t >= off) ? sc[t - off] : 0u;
        __syncthreads();
        sc[t] += a;
        __syncthreads();
    }
    if (t < nloc) {
        unsigned beg = (unsigned)b * PSTRIDE + (sc[t] - pcnt);
        rowinfo[dst0 + t] = (unsigned long long)beg | ((unsigned long long)pcnt << 32);
        dinv[dst0 + t] = rsqrtf((float)(c + 1u));
    }
}

// scatter (src, dinv[src]) pairs + zero-coef padding
__global__ __launch_bounds__(256) void k_scatter(const unsigned* __restrict__ part,
                                                 const unsigned* __restrict__ bcnt,
                                                 const unsigned long long* __restrict__ rowinfo,
                                                 const float* __restrict__ dinv,
                                                 uint2* __restrict__ pairs, int n) {
    __shared__ unsigned cur[256];
    __shared__ unsigned pend[256];
    int b = blockIdx.x;
    int cnt = (int)min(bcnt[b], (unsigned)RCAP);
    unsigned base = b * RCAP;
    int dst0 = b << 8;
    int nloc = min(256, n - dst0);
    int t = threadIdx.x;
    if (t < nloc) {
        unsigned long long ri = rowinfo[dst0 + t];
        cur[t] = (unsigned)ri;
        pend[t] = (unsigned)ri + (unsigned)(ri >> 32);
    } else {
        cur[t] = 0;
        pend[t] = 0;
    }
    __syncthreads();
    for (int i = t; i < cnt; i += 256) {
        unsigned p = part[base + i];
        unsigned loc = p >> 24;
        unsigned s = p & 0xFFFFFFu;
        unsigned pos = atomicAdd(&cur[loc], 1u);
        pairs[pos] = make_uint2(s, __float_as_uint(dinv[s]));
    }
    __syncthreads();
    if (t < nloc) {
        for (unsigned pos = cur[t]; pos < pend[t]; ++pos) pairs[pos] = make_uint2(0u, 0u);
    }
}

// H1[n,64](bf16) = X[n,128](f32) @ W[128,64](f32)
__global__ __launch_bounds__(256) void k_gemm1(const float* __restrict__ X,
                                               const float* __restrict__ W,
                                               unsigned short* __restrict__ H, int n) {
    __shared__ float w[128 * 64];
    const float4* W4 = (const float4*)W;
    for (int i = threadIdx.x; i < 128 * 16; i += 256) ((float4*)w)[i] = W4[i];
    __syncthreads();
    int lane = threadIdx.x & 63, wave = threadIdx.x >> 6;
    int kq = lane >> 4, cg = (lane & 15) * 4;
    int r0 = (blockIdx.x * 4 + wave) * 4;
    if (r0 >= n) return;
    float4 acc[4];
#pragma unroll
    for (int r = 0; r < 4; ++r) acc[r] = make_float4(0.f, 0.f, 0.f, 0.f);
#pragma unroll 8
    for (int k0 = 0; k0 < 128; k0 += 4) {
        int k = k0 + kq;
        float4 wv = *(const float4*)&w[k * 64 + cg];
#pragma unroll
        for (int r = 0; r < 4; ++r) {
            int rr = min(r0 + r, n - 1);
            float xv = X[(size_t)rr * 128 + k];
            acc[r].x += xv * wv.x;
            acc[r].y += xv * wv.y;
            acc[r].z += xv * wv.z;
            acc[r].w += xv * wv.w;
        }
    }
#pragma unroll
    for (int r = 0; r < 4; ++r) {
        float4 a = acc[r];
        a.x += __shfl_xor(a.x, 16, 64); a.y += __shfl_xor(a.y, 16, 64);
        a.z += __shfl_xor(a.z, 16, 64); a.w += __shfl_xor(a.w, 16, 64);
        a.x += __shfl_xor(a.x, 32, 64); a.y += __shfl_xor(a.y, 32, 64);
        a.z += __shfl_xor(a.z, 32, 64); a.w += __shfl_xor(a.w, 32, 64);
        if (kq == 0 && r0 + r < n) {
            ushort4 p;
            p.x = f2b(a.x); p.y = f2b(a.y); p.z = f2b(a.z); p.w = f2b(a.w);
            *(ushort4*)&H[(size_t)(r0 + r) * 64 + cg] = p;
        }
    }
}

// H2[n,20](bf16 pairs) = Xb[n,64](bf16) @ W2[64,40](f32)
__global__ __launch_bounds__(256) void k_gemm2(const unsigned short* __restrict__ X,
                                               const float* __restrict__ W,
                                               unsigned* __restrict__ H, int n) {
    __shared__ float w[64 * 64];
    for (int i = threadIdx.x; i < 64 * 64; i += 256) {
        int k = i >> 6, c = i & 63;
        w[i] = (c < 40) ? W[k * 40 + c] : 0.f;
    }
    __syncthreads();
    int lane = threadIdx.x & 63, wave = threadIdx.x >> 6;
    int kq = lane >> 4, cg = (lane & 15) * 4;
    int r0 = (blockIdx.x * 4 + wave) * 4;
    if (r0 >= n) return;
    float4 acc[4];
#pragma unroll
    for (int r = 0; r < 4; ++r) acc[r] = make_float4(0.f, 0.f, 0.f, 0.f);
#pragma unroll 8
    for (int k0 = 0; k0 < 64; k0 += 4) {
        int k = k0 + kq;
        float4 wv = *(const float4*)&w[k * 64 + cg];
#pragma unroll
        for (int r = 0; r < 4; ++r) {
            int rr = min(r0 + r, n - 1);
            float xv = b2f_lo((unsigned)X[(size_t)rr * 64 + k]);
            acc[r].x += xv * wv.x;
            acc[r].y += xv * wv.y;
            acc[r].z += xv * wv.z;
            acc[r].w += xv * wv.w;
        }
    }
#pragma unroll
    for (int r = 0; r < 4; ++r) {
        float4 a = acc[r];
        a.x += __shfl_xor(a.x, 16, 64); a.y += __shfl_xor(a.y, 16, 64);
        a.z += __shfl_xor(a.z, 16, 64); a.w += __shfl_xor(a.w, 16, 64);
        a.x += __shfl_xor(a.x, 32, 64); a.y += __shfl_xor(a.y, 32, 64);
        a.z += __shfl_xor(a.z, 32, 64); a.w += __shfl_xor(a.w, 32, 64);
        if (kq == 0 && cg < 40 && r0 + r < n) {
            uint2 p;
            p.x = pk2(a.x, a.y);
            p.y = pk2(a.z, a.w);
            *(uint2*)&H[(size_t)(r0 + r) * 20 + (cg >> 1)] = p;
        }
    }
}

// Layer-1 fused gather + epilogue. Wave = node; halves take runs of 4 edges;
// c2 = lane&31 covers bf16 channel pair. Pair stream: (idx, coef) uint2.
__global__ __launch_bounds__(256) void k_conv1(const unsigned long long* __restrict__ rowinfo,
                                               const uint2* __restrict__ pairs,
                                               const float* __restrict__ dinv,
                                               const unsigned* __restrict__ h1,
                                               unsigned* __restrict__ x,
                                               const float* __restrict__ A1,
                                               const float* __restrict__ S1,
                                               const float* __restrict__ k2p,
                                               float* __restrict__ partial, int n) {
    int lane = threadIdx.x & 63, wave = threadIdx.x >> 6;
    int half = lane >> 5, c2 = lane & 31;
    int node = blockIdx.x * 4 + wave;
    float r2 = 0.0f;
    if (node < n) {
        unsigned long long ri = rowinfo[node];
        unsigned beg = (unsigned)ri, pdeg = (unsigned)(ri >> 32);
        float dd = dinv[node];
        unsigned hp = h1[(unsigned)node * 32u + (unsigned)c2];
        float hx = b2f_lo(hp), hy = b2f_hi(hp);
        float ax = half ? 0.f : dd * hx;
        float ay = half ? 0.f : dd * hy;
        for (unsigned eb = 0; eb < pdeg; eb += 8) {
            unsigned bi = beg + eb + (unsigned)half * 4u;
            uint4 q0 = *(const uint4*)&pairs[bi];
            uint4 q1 = *(const uint4*)&pairs[bi + 2];
            unsigned p0 = h1[(q0.x << 5) + (unsigned)c2];
            unsigned p1 = h1[(q0.z << 5) + (unsigned)c2];
            unsigned p2 = h1[(q1.x << 5) + (unsigned)c2];
            unsigned p3 = h1[(q1.z << 5) + (unsigned)c2];
            float c0 = __uint_as_float(q0.y), c1 = __uint_as_float(q0.w);
            float c2f = __uint_as_float(q1.y), c3 = __uint_as_float(q1.w);
            ax += c0 * b2f_lo(p0); ay += c0 * b2f_hi(p0);
            ax += c1 * b2f_lo(p1); ay += c1 * b2f_hi(p1);
            ax += c2f * b2f_lo(p2); ay += c2f * b2f_hi(p2);
            ax += c3 * b2f_lo(p3); ay += c3 * b2f_hi(p3);
        }
        ax += __shfl_xor(ax, 32, 64);
        ay += __shfl_xor(ay, 32, 64);
        if (half == 0) {
            float a_x = dd * ax, a_y = dd * ay;
            float k2 = k2p[0];
            float rx = a_x + (k2 - 1.0f) * hx;
            float ry = a_y + (k2 - 1.0f) * hy;
            r2 = rx * rx + ry * ry;
            float2 Ap = *(const float2*)&A1[2 * c2];
            float2 Sp = *(const float2*)&S1[2 * c2];
            float xnx = tanh_fast((a_x + k2 * hx) * Ap.x + Sp.x);
            float xny = tanh_fast((a_y + k2 * hy) * Ap.y + Sp.y);
            x[(unsigned)node * 32u + (unsigned)c2] = pk2(xnx, xny);
        }
    }
    for (int off = 32; off; off >>= 1) r2 += __shfl_xor(r2, off, 64);
    __shared__ float red[4];
    if (lane == 0) red[wave] = r2;
    __syncthreads();
    if (threadIdx.x == 0) partial[blockIdx.x] = red[0] + red[1] + red[2] + red[3];
}

__global__ __launch_bounds__(1024) void k_loss(const float* __restrict__ partial,
                                               int nparts, float* __restrict__ out,
                                               size_t idx, float inv_cnt) {
    float s = 0.f;
    for (int i = threadIdx.x; i < nparts; i += 1024) s += partial[i];
    for (int off = 32; off; off >>= 1) s += __shfl_xor(s, off, 64);
    __shared__ float red[16];
    int wv = threadIdx.x >> 6, ln = threadIdx.x & 63;
    if (ln == 0) red[wv] = s;
    __syncthreads();
    if (threadIdx.x == 0) {
        float t = 0.f;
        for (int i = 0; i < 16; ++i) t += red[i];
        out[idx] = t * inv_cnt;
    }
}

// Layer-2 fused gather + BN + tanh + log_softmax at batch nodes only.
// h2 is bf16 pairs [n,20]; lanes with c2<20 active per half.
__global__ __launch_bounds__(256) void k_conv2(const int* __restrict__ bn,
                                               const unsigned long long* __restrict__ rowinfo,
                                               const uint2* __restrict__ pairs,
                                               const float* __restrict__ dinv,
                                               const unsigned* __restrict__ h2,
                                               const float* __restrict__ A2,
                                               const float* __restrict__ S2,
                                               const float* __restrict__ k2p,
                                               float* __restrict__ out, int nb) {
    int lane = threadIdx.x & 63, wave = threadIdx.x >> 6;
    int wid = blockIdx.x * 4 + wave;
    if (wid >= nb) return;
    int half = lane >> 5, c2 = lane & 31;
    unsigned p = (unsigned)min(c2, 19);
    int node = bn[wid];
    unsigned long long ri = rowinfo[node];
    unsigned beg = (unsigned)ri, pdeg = (unsigned)(ri >> 32);
    float dd = dinv[node];
    unsigned hp = h2[(unsigned)node * 20u + p];
    float hx = b2f_lo(hp), hy = b2f_hi(hp);
    float ax = half ? 0.f : dd * hx;
    float ay = half ? 0.f : dd * hy;
    for (unsigned eb = 0; eb < pdeg; eb += 8) {
        unsigned bi = beg + eb + (unsigned)half * 4u;
        uint4 q0 = *(const uint4*)&pairs[bi];
        uint4 q1 = *(const uint4*)&pairs[bi + 2];
        unsigned p0 = h2[q0.x * 20u + p];
        unsigned p1 = h2[q0.z * 20u + p];
        unsigned p2 = h2[q1.x * 20u + p];
        unsigned p3 = h2[q1.z * 20u + p];
        float c0 = __uint_as_float(q0.y), c1 = __uint_as_float(q0.w);
        float c2f = __uint_as_float(q1.y), c3 = __uint_as_float(q1.w);
        ax += c0 * b2f_lo(p0); ay += c0 * b2f_hi(p0);
        ax += c1 * b2f_lo(p1); ay += c1 * b2f_hi(p1);
        ax += c2f * b2f_lo(p2); ay += c2f * b2f_hi(p2);
        ax += c3 * b2f_lo(p3); ay += c3 * b2f_hi(p3);
    }
    ax += __shfl_xor(ax, 32, 64);
    ay += __shfl_xor(ay, 32, 64);
    float k2 = k2p[0];
    float2 Ap = *(const float2*)&A2[2 * p];
    float2 Sp = *(const float2*)&S2[2 * p];
    float tx = tanh_fast((dd * ax + k2 * hx) * Ap.x + Sp.x);
    float ty = tanh_fast((dd * ay + k2 * hy) * Ap.y + Sp.y);
    bool act = (half == 0) && (c2 < 20);
    float mx = act ? fmaxf(tx, ty) : -INFINITY;
    for (int off = 32; off; off >>= 1) mx = fmaxf(mx, __shfl_xor(mx, off, 64));
    float es = act ? (__expf(tx - mx) + __expf(ty - mx)) : 0.f;
    for (int off = 32; off; off >>= 1) es += __shfl_xor(es, off, 64);
    if (act) {
        float ls = mx + __logf(es);
        float2 o = make_float2(tx - ls, ty - ls);
        *(float2*)&out[(size_t)wid * 40 + 2 * p] = o;
    }
}

extern "C" void kernel_launch(void* const* d_in, const int* in_sizes, int n_in,
                              void* d_out, int out_size, void* d_ws, size_t ws_size,
                              hipStream_t stream) {
    const float* features = (const float*)d_in[0];
    const int* edge_index = (const int*)d_in[1];
    const int* batch_nodes = (const int*)d_in[2];
    const float* W1 = (const float*)d_in[3];
    const float* b1 = (const float*)d_in[4];
    const float* k2_1 = (const float*)d_in[5];
    const float* W2 = (const float*)d_in[6];
    const float* b2 = (const float*)d_in[7];
    const float* k2_2 = (const float*)d_in[8];
    const float* g1 = (const float*)d_in[9];
    const float* be1 = (const float*)d_in[10];
    const float* m1 = (const float*)d_in[11];
    const float* v1 = (const float*)d_in[12];
    const float* g2 = (const float*)d_in[13];
    const float* be2 = (const float*)d_in[14];
    const float* m2 = (const float*)d_in[15];
    const float* v2 = (const float*)d_in[16];

    const int N = in_sizes[0] / 128;
    const int E = in_sizes[1] / 2;
    const int NB = in_sizes[2];
    const int* src = edge_index;
    const int* dst = edge_index + E;
    const int NPART = (N + 3) / 4;
    const int NBKT = (N + 255) >> 8;   // <= 512
    const int PBLK = 96;

    unsigned* ws = (unsigned*)d_ws;
    auto align64 = [](size_t o) { return (o + 63) & ~(size_t)63; };
    size_t o = 0;
    unsigned long long* rowinfo = (unsigned long long*)(ws + o); o = align64(o + 2 * (size_t)N);
    float* dinv = (float*)(ws + o);       o = align64(o + N);
    float* A1 = (float*)(ws + o);         o = align64(o + 64);
    float* S1 = (float*)(ws + o);         o = align64(o + 64);
    float* A2 = (float*)(ws + o);         o = align64(o + 64);
    float* S2 = (float*)(ws + o);         o = align64(o + 64);
    unsigned* bcnt = ws + o;              o = align64(o + NB_BKT);
    float* partial = (float*)(ws + o);    o = align64(o + NPART);
    uint2* pairs = (uint2*)(ws + o);      o = align64(o + 2 * (size_t)NB_BKT * PSTRIDE);
    unsigned* h1 = ws + o;                o = align64(o + (size_t)N * 32);
    unsigned* x = ws + o;                 o = align64(o + (size_t)N * 32);
    unsigned* h2 = ws + o;                o = align64(o + (size_t)N * 20);
    unsigned* part = h1;  // part (9.4 MB) aliases h1 (12.8 MB): dead before gemm1

    k_init<<<1, 512, 0, stream>>>(bcnt, b1, g1, be1, m1, v1, b2, g2, be2, m2, v2,
                                  A1, S1, A2, S2);
    k_part<<<PBLK, 256, 0, stream>>>(src, dst, E, bcnt, part, PBLK);
    k_deg<<<NBKT, 256, 0, stream>>>(part, bcnt, rowinfo, dinv, N);
    k_scatter<<<NBKT, 256, 0, stream>>>(part, bcnt, rowinfo, dinv, pairs, N);

    k_gemm1<<<(N + 15) / 16, 256, 0, stream>>>(features, W1, (unsigned short*)h1, N);
    k_conv1<<<NPART, 256, 0, stream>>>(rowinfo, pairs, dinv, h1, x, A1, S1, k2_1,
                                       partial, N);
    k_loss<<<1, 1024, 0, stream>>>(partial, NPART, (float*)d_out, (size_t)NB * 40,
                                   1.0f / ((float)N * 64.0f));
    k_gemm2<<<(N + 15) / 16, 256, 0, stream>>>((const unsigned short*)x, W2, h2, N);
    k_conv2<<<(NB + 3) / 4, 256, 0, stream>>>(batch_nodes, rowinfo, pairs, dinv, h2,
                                              A2, S2, k2_2, (float*)d_out, NB);
}

// Round 6
// 247.935 us; speedup vs baseline: 4.2903x; 1.3041x over previous
//
#include <hip/hip_runtime.h>
#include <math.h>

// ---------------------------------------------------------------------------
// HelmholtzGCN forward. R6: MFMA (bf16 16x16x32) for both GEMMs.
//   CSR build: k_init -> k_part (256 blocks) -> k_deg -> k_scatter
//   gemm1 (MFMA, fp32 X -> bf16 frags) -> conv1 (pair-stream gather + BN/tanh
//   + loss) -> gemm2 (MFMA, bf16 in/out) -> conv2 (gather + softmax @ batch).
// ---------------------------------------------------------------------------

#define BN_EPS 1e-5f
#define NB_BKT 512
#define RCAP 4608      // raw per-bucket capacity (mean 3125)
#define PSTRIDE 6656   // padded per-bucket stride

typedef __attribute__((ext_vector_type(8))) short bf16x8;
typedef __attribute__((ext_vector_type(4))) float f32x4;

__device__ inline unsigned short f2b(float f) {
    unsigned u = __float_as_uint(f);
    unsigned r = (u + 0x7fffu + ((u >> 16) & 1u)) >> 16;
    return (unsigned short)r;
}
__device__ inline float b2f_lo(unsigned u) { return __uint_as_float(u << 16); }
__device__ inline float b2f_hi(unsigned u) { return __uint_as_float(u & 0xffff0000u); }
__device__ inline unsigned pk2(float a, float b) {
    return (unsigned)f2b(a) | ((unsigned)f2b(b) << 16);
}
__device__ inline float tanh_fast(float x) {
    float e = __expf(2.0f * x);
    return 1.0f - 2.0f * __builtin_amdgcn_rcpf(e + 1.0f);
}

__global__ __launch_bounds__(512) void k_init(unsigned* __restrict__ bcnt,
                                              const float* __restrict__ b1,
                                              const float* __restrict__ g1,
                                              const float* __restrict__ be1,
                                              const float* __restrict__ m1,
                                              const float* __restrict__ v1,
                                              const float* __restrict__ b2,
                                              const float* __restrict__ g2,
                                              const float* __restrict__ be2,
                                              const float* __restrict__ m2,
                                              const float* __restrict__ v2,
                                              float* __restrict__ A1,
                                              float* __restrict__ S1,
                                              float* __restrict__ A2,
                                              float* __restrict__ S2) {
    int t = threadIdx.x;
    bcnt[t] = 0;
    if (t < 64) {
        float a = g1[t] * rsqrtf(v1[t] + BN_EPS);
        A1[t] = a;
        S1[t] = (b1[t] - m1[t]) * a + be1[t];
    } else if (t < 104) {
        int c = t - 64;
        float a = g2[c] * rsqrtf(v2[c] + BN_EPS);
        A2[c] = a;
        S2[c] = (b2[c] - m2[c]) * a + be2[c];
    }
}

// partition edges into fixed-stride buckets; packed u32 = (dst&255)<<24 | src
__global__ __launch_bounds__(256) void k_part(const int* __restrict__ src,
                                              const int* __restrict__ dst, int e,
                                              unsigned* __restrict__ bcnt,
                                              unsigned* __restrict__ part, int nblk) {
    __shared__ unsigned h[NB_BKT];
    __shared__ unsigned gbase[NB_BKT];
    __shared__ unsigned cur[NB_BKT];
    int chunk = ((e + nblk - 1) / nblk + 3) & ~3;
    int c0 = blockIdx.x * chunk;
    int c1 = min(c0 + chunk, e);
    if (c0 >= e) return;
    for (int i = threadIdx.x; i < NB_BKT; i += 256) h[i] = 0;
    __syncthreads();
    for (int i = c0 + threadIdx.x * 4; i < c1; i += 1024) {
        if (i + 3 < c1) {
            int4 d = *(const int4*)&dst[i];
            atomicAdd(&h[(unsigned)d.x >> 8], 1u);
            atomicAdd(&h[(unsigned)d.y >> 8], 1u);
            atomicAdd(&h[(unsigned)d.z >> 8], 1u);
            atomicAdd(&h[(unsigned)d.w >> 8], 1u);
        } else {
            for (int j = i; j < c1; ++j) atomicAdd(&h[(unsigned)dst[j] >> 8], 1u);
        }
    }
    __syncthreads();
    for (int i = threadIdx.x; i < NB_BKT; i += 256) {
        unsigned c = h[i];
        gbase[i] = c ? (i * RCAP + atomicAdd(&bcnt[i], c)) : 0u;
        cur[i] = 0;
    }
    __syncthreads();
    for (int i = c0 + threadIdx.x * 4; i < c1; i += 1024) {
        if (i + 3 < c1) {
            int4 s = *(const int4*)&src[i];
            int4 d = *(const int4*)&dst[i];
            unsigned b0 = (unsigned)d.x >> 8, b1 = (unsigned)d.y >> 8;
            unsigned b2 = (unsigned)d.z >> 8, b3 = (unsigned)d.w >> 8;
            unsigned p0 = gbase[b0] + atomicAdd(&cur[b0], 1u);
            unsigned p1 = gbase[b1] + atomicAdd(&cur[b1], 1u);
            unsigned p2 = gbase[b2] + atomicAdd(&cur[b2], 1u);
            unsigned p3 = gbase[b3] + atomicAdd(&cur[b3], 1u);
            if (p0 < (b0 + 1) * RCAP) part[p0] = (((unsigned)d.x & 255u) << 24) | (unsigned)s.x;
            if (p1 < (b1 + 1) * RCAP) part[p1] = (((unsigned)d.y & 255u) << 24) | (unsigned)s.y;
            if (p2 < (b2 + 1) * RCAP) part[p2] = (((unsigned)d.z & 255u) << 24) | (unsigned)s.z;
            if (p3 < (b3 + 1) * RCAP) part[p3] = (((unsigned)d.w & 255u) << 24) | (unsigned)s.w;
        } else {
            for (int j = i; j < c1; ++j) {
                unsigned b = (unsigned)dst[j] >> 8;
                unsigned p = gbase[b] + atomicAdd(&cur[b], 1u);
                if (p < (b + 1) * RCAP)
                    part[p] = (((unsigned)dst[j] & 255u) << 24) | (unsigned)src[j];
            }
        }
    }
}

// per-bucket degree/dinv + padded row offsets (rowinfo = beg | pdeg<<32)
__global__ __launch_bounds__(256) void k_deg(const unsigned* __restrict__ part,
                                             const unsigned* __restrict__ bcnt,
                                             unsigned long long* __restrict__ rowinfo,
                                             float* __restrict__ dinv, int n) {
    __shared__ unsigned hist[256];
    __shared__ unsigned sc[256];
    int b = blockIdx.x;
    int cnt = (int)min(bcnt[b], (unsigned)RCAP);
    unsigned base = b * RCAP;
    int dst0 = b << 8;
    int nloc = min(256, n - dst0);
    int t = threadIdx.x;
    hist[t] = 0;
    __syncthreads();
    for (int i = t; i < cnt; i += 256) atomicAdd(&hist[part[base + i] >> 24], 1u);
    __syncthreads();
    unsigned c = hist[t];
    unsigned pcnt = (t < nloc) ? ((c + 7u) & ~7u) : 0u;
    sc[t] = pcnt;
    __syncthreads();
    for (int off = 1; off < 256; off <<= 1) {
        unsigned a = (t >= off) ? sc[t - off] : 0u;
        __syncthreads();
        sc[t] += a;
        __syncthreads();
    }
    if (t < nloc) {
        unsigned beg = (unsigned)b * PSTRIDE + (sc[t] - pcnt);
        rowinfo[dst0 + t] = (unsigned long long)beg | ((unsigned long long)pcnt << 32);
        dinv[dst0 + t] = rsqrtf((float)(c + 1u));
    }
}

// scatter (src, dinv[src]) pairs + zero-coef padding
__global__ __launch_bounds__(256) void k_scatter(const unsigned* __restrict__ part,
                                                 const unsigned* __restrict__ bcnt,
                                                 const unsigned long long* __restrict__ rowinfo,
                                                 const float* __restrict__ dinv,
                                                 uint2* __restrict__ pairs, int n) {
    __shared__ unsigned cur[256];
    __shared__ unsigned pend[256];
    int b = blockIdx.x;
    int cnt = (int)min(bcnt[b], (unsigned)RCAP);
    unsigned base = b * RCAP;
    int dst0 = b << 8;
    int nloc = min(256, n - dst0);
    int t = threadIdx.x;
    if (t < nloc) {
        unsigned long long ri = rowinfo[dst0 + t];
        cur[t] = (unsigned)ri;
        pend[t] = (unsigned)ri + (unsigned)(ri >> 32);
    } else {
        cur[t] = 0;
        pend[t] = 0;
    }
    __syncthreads();
    for (int i = t; i < cnt; i += 256) {
        unsigned p = part[base + i];
        unsigned loc = p >> 24;
        unsigned s = p & 0xFFFFFFu;
        unsigned pos = atomicAdd(&cur[loc], 1u);
        pairs[pos] = make_uint2(s, __float_as_uint(dinv[s]));
    }
    __syncthreads();
    if (t < nloc) {
        for (unsigned pos = cur[t]; pos < pend[t]; ++pos) pairs[pos] = make_uint2(0u, 0u);
    }
}

// H1[n,32 u32 pairs](bf16) = X[n,128](f32) @ W[128,64](f32), via MFMA.
// Wave = 16x64 tile; block = 64 rows. W pre-swizzled to B-frags in LDS.
__global__ __launch_bounds__(256) void k_gemm1(const float* __restrict__ X,
                                               const float* __restrict__ W,
                                               unsigned* __restrict__ H, int n) {
    __shared__ short wb[4][4][64][8];   // B-frags, 16 KB
    __shared__ float cbuf[4][16][65];   // transpose buf, 16.6 KB
    int t = threadIdx.x;
    for (int s = t; s < 1024; s += 256) {
        int l = s & 63, nt = (s >> 6) & 3, kt = s >> 8;
        int kbase = kt * 32 + ((l >> 4) << 3);
        int nn = nt * 16 + (l & 15);
        bf16x8 v;
#pragma unroll
        for (int j = 0; j < 8; ++j) v[j] = (short)f2b(W[(kbase + j) * 64 + nn]);
        *(bf16x8*)&wb[kt][nt][l][0] = v;
    }
    __syncthreads();
    int lane = t & 63, wave = t >> 6;
    int quad = lane >> 4, m = lane & 15;
    int r0 = blockIdx.x * 64 + wave * 16;
    f32x4 acc[4];
#pragma unroll
    for (int i = 0; i < 4; ++i) acc[i] = (f32x4){0.f, 0.f, 0.f, 0.f};
    int rr = min(r0 + m, n - 1);
    const float* xrow = X + (size_t)rr * 128;
#pragma unroll
    for (int kt = 0; kt < 4; ++kt) {
        int kb = kt * 32 + quad * 8;
        float4 x0 = *(const float4*)&xrow[kb];
        float4 x1 = *(const float4*)&xrow[kb + 4];
        bf16x8 af;
        af[0] = (short)f2b(x0.x); af[1] = (short)f2b(x0.y);
        af[2] = (short)f2b(x0.z); af[3] = (short)f2b(x0.w);
        af[4] = (short)f2b(x1.x); af[5] = (short)f2b(x1.y);
        af[6] = (short)f2b(x1.z); af[7] = (short)f2b(x1.w);
#pragma unroll
        for (int nt = 0; nt < 4; ++nt) {
            bf16x8 bf = *(bf16x8*)&wb[kt][nt][lane][0];
            acc[nt] = __builtin_amdgcn_mfma_f32_16x16x32_bf16(af, bf, acc[nt], 0, 0, 0);
        }
    }
#pragma unroll
    for (int nt = 0; nt < 4; ++nt)
#pragma unroll
        for (int r = 0; r < 4; ++r)
            cbuf[wave][quad * 4 + r][nt * 16 + m] = acc[nt][r];
    __syncthreads();
#pragma unroll
    for (int i = 0; i < 8; ++i) {
        int f = i * 64 + lane;
        int row = f >> 5, cp = f & 31;
        int grow = r0 + row;
        if (grow < n)
            H[(size_t)grow * 32 + cp] =
                pk2(cbuf[wave][row][2 * cp], cbuf[wave][row][2 * cp + 1]);
    }
}

// H2[n,20 u32 pairs](bf16) = Xb[n,64](bf16) @ W2[64,40](f32), via MFMA.
// N padded 40->48 (3 n-tiles); A-frags load directly from bf16 X.
__global__ __launch_bounds__(256) void k_gemm2(const unsigned short* __restrict__ X,
                                               const float* __restrict__ W,
                                               unsigned* __restrict__ H, int n) {
    __shared__ short wb[2][3][64][8];   // 6 KB
    __shared__ float cbuf[4][16][49];   // 12.5 KB
    int t = threadIdx.x;
    for (int s = t; s < 384; s += 256) {
        int l = s & 63, nt = (s >> 6) % 3, kt = s / 192;
        int kbase = kt * 32 + ((l >> 4) << 3);
        int c = nt * 16 + (l & 15);
        bf16x8 v;
#pragma unroll
        for (int j = 0; j < 8; ++j)
            v[j] = (c < 40) ? (short)f2b(W[(kbase + j) * 40 + c]) : (short)0;
        *(bf16x8*)&wb[kt][nt][l][0] = v;
    }
    __syncthreads();
    int lane = t & 63, wave = t >> 6;
    int quad = lane >> 4, m = lane & 15;
    int r0 = blockIdx.x * 64 + wave * 16;
    f32x4 acc[3];
#pragma unroll
    for (int i = 0; i < 3; ++i) acc[i] = (f32x4){0.f, 0.f, 0.f, 0.f};
    int rr = min(r0 + m, n - 1);
    const unsigned short* xrow = X + (size_t)rr * 64;
#pragma unroll
    for (int kt = 0; kt < 2; ++kt) {
        bf16x8 af = *(const bf16x8*)&xrow[kt * 32 + quad * 8];
#pragma unroll
        for (int nt = 0; nt < 3; ++nt) {
            bf16x8 bf = *(bf16x8*)&wb[kt][nt][lane][0];
            acc[nt] = __builtin_amdgcn_mfma_f32_16x16x32_bf16(af, bf, acc[nt], 0, 0, 0);
        }
    }
#pragma unroll
    for (int nt = 0; nt < 3; ++nt)
#pragma unroll
        for (int r = 0; r < 4; ++r)
            cbuf[wave][quad * 4 + r][nt * 16 + m] = acc[nt][r];
    __syncthreads();
#pragma unroll
    for (int i = 0; i < 5; ++i) {
        int f = i * 64 + lane;
        int row = f / 20, cp = f % 20;
        int grow = r0 + row;
        if (grow < n)
            H[(size_t)grow * 20 + cp] =
                pk2(cbuf[wave][row][2 * cp], cbuf[wave][row][2 * cp + 1]);
    }
}

// Layer-1 fused gather + epilogue. Wave = node; halves take runs of 4 edges;
// c2 = lane&31 covers bf16 channel pair. Pair stream: (idx, coef) uint2.
__global__ __launch_bounds__(256) void k_conv1(const unsigned long long* __restrict__ rowinfo,
                                               const uint2* __restrict__ pairs,
                                               const float* __restrict__ dinv,
                                               const unsigned* __restrict__ h1,
                                               unsigned* __restrict__ x,
                                               const float* __restrict__ A1,
                                               const float* __restrict__ S1,
                                               const float* __restrict__ k2p,
                                               float* __restrict__ partial, int n) {
    int lane = threadIdx.x & 63, wave = threadIdx.x >> 6;
    int half = lane >> 5, c2 = lane & 31;
    int node = blockIdx.x * 4 + wave;
    float r2 = 0.0f;
    if (node < n) {
        unsigned long long ri = rowinfo[node];
        unsigned beg = (unsigned)ri, pdeg = (unsigned)(ri >> 32);
        float dd = dinv[node];
        unsigned hp = h1[(unsigned)node * 32u + (unsigned)c2];
        float hx = b2f_lo(hp), hy = b2f_hi(hp);
        float ax = half ? 0.f : dd * hx;
        float ay = half ? 0.f : dd * hy;
        for (unsigned eb = 0; eb < pdeg; eb += 8) {
            unsigned bi = beg + eb + (unsigned)half * 4u;
            uint4 q0 = *(const uint4*)&pairs[bi];
            uint4 q1 = *(const uint4*)&pairs[bi + 2];
            unsigned p0 = h1[(q0.x << 5) + (unsigned)c2];
            unsigned p1 = h1[(q0.z << 5) + (unsigned)c2];
            unsigned p2 = h1[(q1.x << 5) + (unsigned)c2];
            unsigned p3 = h1[(q1.z << 5) + (unsigned)c2];
            float c0 = __uint_as_float(q0.y), c1 = __uint_as_float(q0.w);
            float c2f = __uint_as_float(q1.y), c3 = __uint_as_float(q1.w);
            ax += c0 * b2f_lo(p0); ay += c0 * b2f_hi(p0);
            ax += c1 * b2f_lo(p1); ay += c1 * b2f_hi(p1);
            ax += c2f * b2f_lo(p2); ay += c2f * b2f_hi(p2);
            ax += c3 * b2f_lo(p3); ay += c3 * b2f_hi(p3);
        }
        ax += __shfl_xor(ax, 32, 64);
        ay += __shfl_xor(ay, 32, 64);
        if (half == 0) {
            float a_x = dd * ax, a_y = dd * ay;
            float k2 = k2p[0];
            float rx = a_x + (k2 - 1.0f) * hx;
            float ry = a_y + (k2 - 1.0f) * hy;
            r2 = rx * rx + ry * ry;
            float2 Ap = *(const float2*)&A1[2 * c2];
            float2 Sp = *(const float2*)&S1[2 * c2];
            float xnx = tanh_fast((a_x + k2 * hx) * Ap.x + Sp.x);
            float xny = tanh_fast((a_y + k2 * hy) * Ap.y + Sp.y);
            x[(unsigned)node * 32u + (unsigned)c2] = pk2(xnx, xny);
        }
    }
    for (int off = 32; off; off >>= 1) r2 += __shfl_xor(r2, off, 64);
    __shared__ float red[4];
    if (lane == 0) red[wave] = r2;
    __syncthreads();
    if (threadIdx.x == 0) partial[blockIdx.x] = red[0] + red[1] + red[2] + red[3];
}

__global__ __launch_bounds__(1024) void k_loss(const float* __restrict__ partial,
                                               int nparts, float* __restrict__ out,
                                               size_t idx, float inv_cnt) {
    float s = 0.f;
    for (int i = threadIdx.x; i < nparts; i += 1024) s += partial[i];
    for (int off = 32; off; off >>= 1) s += __shfl_xor(s, off, 64);
    __shared__ float red[16];
    int wv = threadIdx.x >> 6, ln = threadIdx.x & 63;
    if (ln == 0) red[wv] = s;
    __syncthreads();
    if (threadIdx.x == 0) {
        float t = 0.f;
        for (int i = 0; i < 16; ++i) t += red[i];
        out[idx] = t * inv_cnt;
    }
}

// Layer-2 fused gather + BN + tanh + log_softmax at batch nodes only.
__global__ __launch_bounds__(256) void k_conv2(const int* __restrict__ bn,
                                               const unsigned long long* __restrict__ rowinfo,
                                               const uint2* __restrict__ pairs,
                                               const float* __restrict__ dinv,
                                               const unsigned* __restrict__ h2,
                                               const float* __restrict__ A2,
                                               const float* __restrict__ S2,
                                               const float* __restrict__ k2p,
                                               float* __restrict__ out, int nb) {
    int lane = threadIdx.x & 63, wave = threadIdx.x >> 6;
    int wid = blockIdx.x * 4 + wave;
    if (wid >= nb) return;
    int half = lane >> 5, c2 = lane & 31;
    unsigned p = (unsigned)min(c2, 19);
    int node = bn[wid];
    unsigned long long ri = rowinfo[node];
    unsigned beg = (unsigned)ri, pdeg = (unsigned)(ri >> 32);
    float dd = dinv[node];
    unsigned hp = h2[(unsigned)node * 20u + p];
    float hx = b2f_lo(hp), hy = b2f_hi(hp);
    float ax = half ? 0.f : dd * hx;
    float ay = half ? 0.f : dd * hy;
    for (unsigned eb = 0; eb < pdeg; eb += 8) {
        unsigned bi = beg + eb + (unsigned)half * 4u;
        uint4 q0 = *(const uint4*)&pairs[bi];
        uint4 q1 = *(const uint4*)&pairs[bi + 2];
        unsigned p0 = h2[q0.x * 20u + p];
        unsigned p1 = h2[q0.z * 20u + p];
        unsigned p2 = h2[q1.x * 20u + p];
        unsigned p3 = h2[q1.z * 20u + p];
        float c0 = __uint_as_float(q0.y), c1 = __uint_as_float(q0.w);
        float c2f = __uint_as_float(q1.y), c3 = __uint_as_float(q1.w);
        ax += c0 * b2f_lo(p0); ay += c0 * b2f_hi(p0);
        ax += c1 * b2f_lo(p1); ay += c1 * b2f_hi(p1);
        ax += c2f * b2f_lo(p2); ay += c2f * b2f_hi(p2);
        ax += c3 * b2f_lo(p3); ay += c3 * b2f_hi(p3);
    }
    ax += __shfl_xor(ax, 32, 64);
    ay += __shfl_xor(ay, 32, 64);
    float k2 = k2p[0];
    float2 Ap = *(const float2*)&A2[2 * p];
    float2 Sp = *(const float2*)&S2[2 * p];
    float tx = tanh_fast((dd * ax + k2 * hx) * Ap.x + Sp.x);
    float ty = tanh_fast((dd * ay + k2 * hy) * Ap.y + Sp.y);
    bool act = (half == 0) && (c2 < 20);
    float mx = act ? fmaxf(tx, ty) : -INFINITY;
    for (int off = 32; off; off >>= 1) mx = fmaxf(mx, __shfl_xor(mx, off, 64));
    float es = act ? (__expf(tx - mx) + __expf(ty - mx)) : 0.f;
    for (int off = 32; off; off >>= 1) es += __shfl_xor(es, off, 64);
    if (act) {
        float ls = mx + __logf(es);
        float2 o = make_float2(tx - ls, ty - ls);
        *(float2*)&out[(size_t)wid * 40 + 2 * p] = o;
    }
}

extern "C" void kernel_launch(void* const* d_in, const int* in_sizes, int n_in,
                              void* d_out, int out_size, void* d_ws, size_t ws_size,
                              hipStream_t stream) {
    const float* features = (const float*)d_in[0];
    const int* edge_index = (const int*)d_in[1];
    const int* batch_nodes = (const int*)d_in[2];
    const float* W1 = (const float*)d_in[3];
    const float* b1 = (const float*)d_in[4];
    const float* k2_1 = (const float*)d_in[5];
    const float* W2 = (const float*)d_in[6];
    const float* b2 = (const float*)d_in[7];
    const float* k2_2 = (const float*)d_in[8];
    const float* g1 = (const float*)d_in[9];
    const float* be1 = (const float*)d_in[10];
    const float* m1 = (const float*)d_in[11];
    const float* v1 = (const float*)d_in[12];
    const float* g2 = (const float*)d_in[13];
    const float* be2 = (const float*)d_in[14];
    const float* m2 = (const float*)d_in[15];
    const float* v2 = (const float*)d_in[16];

    const int N = in_sizes[0] / 128;
    const int E = in_sizes[1] / 2;
    const int NB = in_sizes[2];
    const int* src = edge_index;
    const int* dst = edge_index + E;
    const int NPART = (N + 3) / 4;
    const int NBKT = (N + 255) >> 8;   // <= 512
    const int PBLK = 256;

    unsigned* ws = (unsigned*)d_ws;
    auto align64 = [](size_t o) { return (o + 63) & ~(size_t)63; };
    size_t o = 0;
    unsigned long long* rowinfo = (unsigned long long*)(ws + o); o = align64(o + 2 * (size_t)N);
    float* dinv = (float*)(ws + o);       o = align64(o + N);
    float* A1 = (float*)(ws + o);         o = align64(o + 64);
    float* S1 = (float*)(ws + o);         o = align64(o + 64);
    float* A2 = (float*)(ws + o);         o = align64(o + 64);
    float* S2 = (float*)(ws + o);         o = align64(o + 64);
    unsigned* bcnt = ws + o;              o = align64(o + NB_BKT);
    float* partial = (float*)(ws + o);    o = align64(o + NPART);
    uint2* pairs = (uint2*)(ws + o);      o = align64(o + 2 * (size_t)NB_BKT * PSTRIDE);
    unsigned* h1 = ws + o;                o = align64(o + (size_t)N * 32);
    unsigned* x = ws + o;                 o = align64(o + (size_t)N * 32);
    unsigned* h2 = ws + o;                o = align64(o + (size_t)N * 20);
    unsigned* part = h1;  // part (9.4 MB) aliases h1 (12.8 MB): dead before gemm1

    k_init<<<1, 512, 0, stream>>>(bcnt, b1, g1, be1, m1, v1, b2, g2, be2, m2, v2,
                                  A1, S1, A2, S2);
    k_part<<<PBLK, 256, 0, stream>>>(src, dst, E, bcnt, part, PBLK);
    k_deg<<<NBKT, 256, 0, stream>>>(part, bcnt, rowinfo, dinv, N);
    k_scatter<<<NBKT, 256, 0, stream>>>(part, bcnt, rowinfo, dinv, pairs, N);

    k_gemm1<<<(N + 63) / 64, 256, 0, stream>>>(features, W1, h1, N);
    k_conv1<<<NPART, 256, 0, stream>>>(rowinfo, pairs, dinv, h1, x, A1, S1, k2_1,
                                       partial, N);
    k_loss<<<1, 1024, 0, stream>>>(partial, NPART, (float*)d_out, (size_t)NB * 40,
                                   1.0f / ((float)N * 64.0f));
    k_gemm2<<<(N + 63) / 64, 256, 0, stream>>>((const unsigned short*)x, W2, h2, N);
    k_conv2<<<(NB + 3) / 4, 256, 0, stream>>>(batch_nodes, rowinfo, pairs, dinv, h2,
                                              A2, S2, k2_2, (float*)d_out, NB);
}